// Round 2
// baseline (12397.326 us; speedup 1.0000x reference)
//
#include <hip/hip_runtime.h>
#include <math.h>

#define BB 4
#define SS 8192
#define HID 256
#define NHEADS 4
#define DH 64
#define FFD 1024
#define NLAYERS 2
#define NHASH 2
#define NBUCK 128
#define NROT 64          // NBUCK/2
#define NSEQ (NHASH*SS)  // 16384
#define NCH (NSEQ/64)    // 256 chunks of 64
#define MASKVAL -1e5f

// ---------------- block reduce (256 threads = 4 waves) ----------------
__device__ __forceinline__ float block_reduce_sum(float v, float* red) {
#pragma unroll
    for (int off = 32; off; off >>= 1) v += __shfl_down(v, off);
    int lane = threadIdx.x & 63, wid = threadIdx.x >> 6;
    __syncthreads();
    if (lane == 0) red[wid] = v;
    __syncthreads();
    return red[0] + red[1] + red[2] + red[3];
}

// ---------------- LayerNorm over 256 ----------------
__global__ void ln256_kernel(const float* __restrict__ x, const float* __restrict__ g,
                             const float* __restrict__ b, float* __restrict__ y) {
    int row = blockIdx.x, tid = threadIdx.x;
    __shared__ float red[4];
    float v = x[(size_t)row * HID + tid];
    float mu = block_reduce_sum(v, red) * (1.f / 256.f);
    float d = v - mu;
    float var = block_reduce_sum(d * d, red) * (1.f / 256.f);
    y[(size_t)row * HID + tid] = d * rsqrtf(var + 1e-12f) * g[tid] + b[tid];
}

// ---------------- Final LayerNorm over concat(512) ----------------
__global__ void ln512_kernel(const float* __restrict__ a, const float* __restrict__ hd,
                             const float* __restrict__ g, const float* __restrict__ b,
                             float* __restrict__ out) {
    int row = blockIdx.x, tid = threadIdx.x;
    __shared__ float red[4];
    float x0 = a[(size_t)row * HID + tid];
    float x1 = hd[(size_t)row * HID + tid];
    float mu = block_reduce_sum(x0 + x1, red) * (1.f / 512.f);
    float d0 = x0 - mu, d1 = x1 - mu;
    float var = block_reduce_sum(d0 * d0 + d1 * d1, red) * (1.f / 512.f);
    float r = rsqrtf(var + 1e-12f);
    out[(size_t)row * 512 + tid]       = d0 * r * g[tid] + b[tid];
    out[(size_t)row * 512 + 256 + tid] = d1 * r * g[256 + tid] + b[256 + tid];
}

// ---------------- fp32 tiled GEMM: C[M,N] = A[M,K] @ B[K,N] (+epilogue) ----------------
// EPI: 0 = store, 1 = store relu(acc+bias), 2 = C += acc, 3 = C += acc + bias
template <int EPI>
__global__ __launch_bounds__(256) void gemm64_kernel(
    const float* __restrict__ A, const float* __restrict__ Bm,
    const float* __restrict__ bias, float* __restrict__ C,
    int M, int N, int K) {
    __shared__ float As[16][64];
    __shared__ float Bs[16][64];
    int bm = blockIdx.x * 64, bn = blockIdx.y * 64;
    int tid = threadIdx.x;
    int tx = tid & 15, ty = tid >> 4;
    float acc[4][4] = {};
    for (int k0 = 0; k0 < K; k0 += 16) {
#pragma unroll
        for (int t = 0; t < 4; ++t) {
            int e = tid + t * 256;
            int m = e >> 4, kk = e & 15;
            As[kk][m] = A[(size_t)(bm + m) * K + k0 + kk];
        }
#pragma unroll
        for (int t = 0; t < 4; ++t) {
            int e = tid + t * 256;
            int kk = e >> 6, n = e & 63;
            Bs[kk][n] = Bm[(size_t)(k0 + kk) * N + bn + n];
        }
        __syncthreads();
#pragma unroll
        for (int kk = 0; kk < 16; ++kk) {
            float a0[4], b0[4];
#pragma unroll
            for (int i = 0; i < 4; ++i) a0[i] = As[kk][ty * 4 + i];
#pragma unroll
            for (int j = 0; j < 4; ++j) b0[j] = Bs[kk][tx * 4 + j];
#pragma unroll
            for (int i = 0; i < 4; ++i)
#pragma unroll
                for (int j = 0; j < 4; ++j) acc[i][j] += a0[i] * b0[j];
        }
        __syncthreads();
    }
#pragma unroll
    for (int i = 0; i < 4; ++i) {
        int m = bm + ty * 4 + i;
        float* Cr = C + (size_t)m * N + bn + tx * 4;
#pragma unroll
        for (int j = 0; j < 4; ++j) {
            float val = acc[i][j];
            if (EPI == 1)      { val += bias[bn + tx * 4 + j]; Cr[j] = fmaxf(val, 0.f); }
            else if (EPI == 2) { Cr[j] += val; }
            else if (EPI == 3) { Cr[j] += val + bias[bn + tx * 4 + j]; }
            else               { Cr[j] = val; }
        }
    }
}

// ---------------- LSH hash: bucket = argmax([rot, -rot]) ----------------
// qk is a per-batch slice [S,HID]; buckets_b is per-batch [H,NSEQ]
__global__ void hash_kernel(const float* __restrict__ qk, const float* __restrict__ rot,
                            int* __restrict__ buckets) {
    int s = blockIdx.x * 256 + threadIdx.x;
    int h = blockIdx.y;
    const float* qr = qk + (size_t)s * HID + h * DH;
    float q[DH];
#pragma unroll
    for (int d = 0; d < DH; ++d) q[d] = qr[d];
    const float* rh = rot + (size_t)h * DH * NHASH * NROT;
    int outb = h * NSEQ;
    for (int n = 0; n < NHASH; ++n) {
        float bestp = -3.4e38f, bestn = -3.4e38f;
        int ip = 0, in_ = 0;
        for (int half = 0; half < 2; ++half) {
            float acc[32] = {};
            for (int d = 0; d < DH; ++d) {
                const float* rp = rh + (size_t)(d * NHASH + n) * NROT + half * 32;
                float qd = q[d];
#pragma unroll
                for (int r4 = 0; r4 < 8; ++r4) {
                    float4 f = *(const float4*)(rp + r4 * 4);
                    acc[r4 * 4 + 0] += qd * f.x;
                    acc[r4 * 4 + 1] += qd * f.y;
                    acc[r4 * 4 + 2] += qd * f.z;
                    acc[r4 * 4 + 3] += qd * f.w;
                }
            }
#pragma unroll
            for (int r = 0; r < 32; ++r) {
                int ri = half * 32 + r;
                if (acc[r] > bestp) { bestp = acc[r]; ip = ri; }
                if (-acc[r] > bestn) { bestn = -acc[r]; in_ = ri; }
            }
        }
        int bucket = (bestn > bestp) ? (NROT + in_) : ip;
        buckets[outb + n * SS + s] = bucket + n * NBUCK;
    }
}

// ---------------- stable counting sort by bucket (one wave per head) ----------------
__global__ void sort_kernel(const int* __restrict__ buckets, int* __restrict__ sort_idx,
                            int* __restrict__ inv) {
    int bh = blockIdx.x;  // head index within this batch
    const int* bk = buckets + (size_t)bh * NSEQ;
    int* sj = sort_idx + (size_t)bh * NSEQ;
    int* ij = inv + (size_t)bh * NSEQ;
    __shared__ int hist[NHASH * NBUCK];  // 256 bins
    int tid = threadIdx.x;  // 64 threads
    for (int t = tid; t < 256; t += 64) hist[t] = 0;
    __syncthreads();
    for (int i = tid; i < NSEQ; i += 64) atomicAdd(&hist[bk[i]], 1);
    __syncthreads();
    if (tid == 0) {
        int run = 0;
        for (int j = 0; j < 256; ++j) { int t = hist[j]; hist[j] = run; run += t; }
    }
    __syncthreads();
    for (int base = 0; base < NSEQ; base += 64) {
        int i = base + tid;
        int b = bk[i];
        int before = 0, total = 0;
        for (int k = 0; k < 64; ++k) {
            int bo = __shfl(b, k);
            before += (k < tid && bo == b) ? 1 : 0;
            total += (bo == b) ? 1 : 0;
        }
        int j = hist[b] + before;
        sj[j] = i;
        ij[i] = j;
        __syncthreads();
        if (before == total - 1) hist[b] += total;
        __syncthreads();
    }
}

// ---------------- chunked LSH attention (one block per h,chunk; per-batch slices) ----------------
#define QPAD 68
__global__ __launch_bounds__(256) void attn_kernel(
    const float* __restrict__ qk, const float* __restrict__ vv,
    const int* __restrict__ sort_idx,
    float* __restrict__ out_s, float* __restrict__ logit_s) {
    __shared__ float q_lds[64][QPAD];
    __shared__ float kv_lds[128][QPAD];
    __shared__ int qid[64];
    __shared__ int kid[128];
    int c = blockIdx.x, h = blockIdx.y;
    int tid = threadIdx.x;
    const int* si = sort_idx + (size_t)h * NSEQ;
    int cprev = (c == 0) ? (NCH - 1) : (c - 1);
    if (tid < 64) qid[tid] = si[c * 64 + tid];
    else if (tid < 192) {
        int k = tid - 64;
        kid[k] = (k < 64) ? si[cprev * 64 + k] : si[c * 64 + (k - 64)];
    }
    __syncthreads();
    // gather Q rows (64 x 64)
#pragma unroll
    for (int t = 0; t < 4; ++t) {
        int e = tid + t * 256;
        int row = e >> 4, d4 = e & 15;
        int s = qid[row] & (SS - 1);
        float4 f = *(const float4*)(qk + (size_t)s * HID + h * DH + d4 * 4);
        *(float4*)&q_lds[row][d4 * 4] = f;
    }
    // gather K rows raw (128 x 64)
#pragma unroll
    for (int t = 0; t < 8; ++t) {
        int e = tid + t * 256;
        int row = e >> 4, d4 = e & 15;
        int s = kid[row] & (SS - 1);
        float4 f = *(const float4*)(qk + (size_t)s * HID + h * DH + d4 * 4);
        *(float4*)&kv_lds[row][d4 * 4] = f;
    }
    __syncthreads();
    // len+dim normalize K rows: k = k / max(||k||,1e-12) * D^-0.5
    if (tid < 128) {
        float ssq = 0;
#pragma unroll
        for (int d = 0; d < DH; ++d) { float x = kv_lds[tid][d]; ssq += x * x; }
        float nrm = fmaxf(sqrtf(ssq), 1e-12f);
        float sc = 0.125f / nrm;
#pragma unroll
        for (int d = 0; d < DH; ++d) kv_lds[tid][d] *= sc;
    }
    __syncthreads();
    int q = tid >> 2, ks = tid & 3;
    int myqid = qid[q];
    float sc_[32];
    float m = -3.4e38f;
#pragma unroll 4
    for (int kk = 0; kk < 32; ++kk) {
        int k = ks + kk * 4;  // interleaved to avoid LDS bank conflicts
        float acc = 0;
#pragma unroll
        for (int d4 = 0; d4 < 16; ++d4) {
            float4 qa = *(float4*)&q_lds[q][d4 * 4];
            float4 ka = *(float4*)&kv_lds[k][d4 * 4];
            acc += qa.x * ka.x + qa.y * ka.y + qa.z * ka.z + qa.w * ka.w;
        }
        if (myqid == kid[k]) acc = MASKVAL;
        sc_[kk] = acc;
        m = fmaxf(m, acc);
    }
    m = fmaxf(m, __shfl_xor(m, 1));
    m = fmaxf(m, __shfl_xor(m, 2));
    float se = 0;
#pragma unroll
    for (int kk = 0; kk < 32; ++kk) se += expf(sc_[kk] - m);
    se += __shfl_xor(se, 1);
    se += __shfl_xor(se, 2);
    float logit = m + logf(se);
#pragma unroll
    for (int kk = 0; kk < 32; ++kk) sc_[kk] = expf(sc_[kk] - logit);  // probs
    __syncthreads();
    // reload V rows (raw gather)
#pragma unroll
    for (int t = 0; t < 8; ++t) {
        int e = tid + t * 256;
        int row = e >> 4, d4 = e & 15;
        int s = kid[row] & (SS - 1);
        float4 f = *(const float4*)(vv + (size_t)s * HID + h * DH + d4 * 4);
        *(float4*)&kv_lds[row][d4 * 4] = f;
    }
    __syncthreads();
    float acc[DH] = {};
#pragma unroll 4
    for (int kk = 0; kk < 32; ++kk) {
        int k = ks + kk * 4;
        float p = sc_[kk];
#pragma unroll
        for (int d4 = 0; d4 < 16; ++d4) {
            float4 va = *(float4*)&kv_lds[k][d4 * 4];
            acc[d4 * 4 + 0] += p * va.x;
            acc[d4 * 4 + 1] += p * va.y;
            acc[d4 * 4 + 2] += p * va.z;
            acc[d4 * 4 + 3] += p * va.w;
        }
    }
#pragma unroll
    for (int d = 0; d < DH; ++d) {
        acc[d] += __shfl_xor(acc[d], 1);
        acc[d] += __shfl_xor(acc[d], 2);
    }
    if (ks == 0) {
        float* dst = out_s + ((size_t)h * NSEQ + c * 64 + q) * DH;
#pragma unroll
        for (int d4 = 0; d4 < 16; ++d4)
            *(float4*)&dst[d4 * 4] = make_float4(acc[d4 * 4], acc[d4 * 4 + 1], acc[d4 * 4 + 2], acc[d4 * 4 + 3]);
        logit_s[(size_t)h * NSEQ + c * 64 + q] = logit;
    }
}

// ---------------- unsort + combine hash rounds (per-batch slices) ----------------
__global__ void combine_kernel(const float* __restrict__ out_s, const float* __restrict__ logit_s,
                               const int* __restrict__ inv, float* __restrict__ attn_comb) {
    size_t gid = (size_t)blockIdx.x * 256 + threadIdx.x;  // H*S*16 threads
    int d4 = gid & 15;
    size_t r = gid >> 4;
    int s = (int)(r & (SS - 1));
    int h = (int)(r >> 13);
    int j0 = inv[(size_t)h * NSEQ + s];
    int j1 = inv[(size_t)h * NSEQ + SS + s];
    float l0 = logit_s[(size_t)h * NSEQ + j0];
    float l1 = logit_s[(size_t)h * NSEQ + j1];
    float mx = fmaxf(l0, l1);
    float e0 = expf(l0 - mx), e1 = expf(l1 - mx);
    float is = 1.f / (e0 + e1);
    float w0 = e0 * is, w1 = e1 * is;
    float4 o0 = *(const float4*)(out_s + ((size_t)h * NSEQ + j0) * DH + d4 * 4);
    float4 o1 = *(const float4*)(out_s + ((size_t)h * NSEQ + j1) * DH + d4 * 4);
    float4 o;
    o.x = w0 * o0.x + w1 * o1.x;
    o.y = w0 * o0.y + w1 * o1.y;
    o.z = w0 * o0.z + w1 * o1.z;
    o.w = w0 * o0.w + w1 * o1.w;
    *(float4*)(attn_comb + (size_t)s * HID + h * DH + d4 * 4) = o;
}

// ---------------- launch ----------------
extern "C" void kernel_launch(void* const* d_in, const int* in_sizes, int n_in,
                              void* d_out, int out_size, void* d_ws, size_t ws_size,
                              hipStream_t stream) {
    const float* hs  = (const float*)d_in[0];
    const float* g1  = (const float*)d_in[1];
    const float* b1  = (const float*)d_in[2];
    const float* Wqk = (const float*)d_in[3];
    const float* Wv  = (const float*)d_in[4];
    const float* Wo  = (const float*)d_in[5];
    const float* rot = (const float*)d_in[6];
    const float* g2  = (const float*)d_in[7];
    const float* b2  = (const float*)d_in[8];
    const float* W1  = (const float*)d_in[9];
    const float* bf1 = (const float*)d_in[10];
    const float* W2  = (const float*)d_in[11];
    const float* bf2 = (const float*)d_in[12];
    const float* gf  = (const float*)d_in[13];
    const float* bff = (const float*)d_in[14];

    const size_t NE  = (size_t)BB * SS * HID;   // 8,388,608 floats
    const size_t NB4 = NE / 4;                  // per-batch [S,HID] = 2,097,152
    float* f = (float*)d_ws;
    float* attn_out = f;                 // [B,S,HID]  persistent
    float* hidden   = f + NE;            // [B,S,HID]  persistent
    float* xln      = f + 2 * NE;        // [S,HID] per-batch (x_ln / comb / h_ln)
    float* bigB     = f + 2 * NE + NB4;  // NE/2: qk_b | v_b, later ffbuf [4096,1024]
    float* qk_b     = bigB;
    float* v_b      = bigB + NB4;
    float* logit_b  = f + 2 * NE + NB4 + NE / 2;            // [H,NSEQ] = 65536
    int*   sort_b   = (int*)(logit_b + (size_t)NHEADS * NSEQ);
    int*   inv_b    = sort_b + (size_t)NHEADS * NSEQ;
    int*   buck_b   = inv_b + (size_t)NHEADS * NSEQ;
    // total ws usage: 2.75*NE + 4*65536 floats  ~= 89.3 MB

    float* outsort = (float*)d_out;  // reuse d_out as [B][H,NSEQ,DH] scratch (16.78M floats)

    hipMemcpyAsync(attn_out, hs, NE * 4, hipMemcpyDeviceToDevice, stream);
    hipMemcpyAsync(hidden, hs, NE * 4, hipMemcpyDeviceToDevice, stream);

    for (int l = 0; l < NLAYERS; ++l) {
        const float* g1l = g1 + l * HID;
        const float* b1l = b1 + l * HID;
        const float* Wqkl = Wqk + (size_t)l * HID * HID;
        const float* Wvl  = Wv + (size_t)l * HID * HID;
        const float* Wol  = Wo + (size_t)l * HID * HID;
        const float* rotl = rot + (size_t)l * NHEADS * DH * NHASH * NROT;
        const float* g2l = g2 + l * HID;
        const float* b2l = b2 + l * HID;
        const float* W1l = W1 + (size_t)l * HID * FFD;
        const float* bf1l = bf1 + l * FFD;
        const float* W2l = W2 + (size_t)l * FFD * HID;
        const float* bf2l = bf2 + l * HID;

        // ---- attention (per batch to bound workspace) ----
        for (int b = 0; b < BB; ++b) {
            const float* hid_b = hidden + (size_t)b * SS * HID;
            float* ao_b = attn_out + (size_t)b * SS * HID;
            float* outs_b = outsort + (size_t)b * NHEADS * NSEQ * DH;
            ln256_kernel<<<SS, 256, 0, stream>>>(hid_b, g1l, b1l, xln);
            gemm64_kernel<0><<<dim3(SS / 64, HID / 64), 256, 0, stream>>>(xln, Wqkl, nullptr, qk_b, SS, HID, HID);
            gemm64_kernel<0><<<dim3(SS / 64, HID / 64), 256, 0, stream>>>(xln, Wvl, nullptr, v_b, SS, HID, HID);
            hash_kernel<<<dim3(SS / 256, NHEADS), 256, 0, stream>>>(qk_b, rotl, buck_b);
            sort_kernel<<<NHEADS, 64, 0, stream>>>(buck_b, sort_b, inv_b);
            attn_kernel<<<dim3(NCH, NHEADS), 256, 0, stream>>>(qk_b, v_b, sort_b, outs_b, logit_b);
            combine_kernel<<<(NHEADS * SS * 16) / 256, 256, 0, stream>>>(outs_b, logit_b, inv_b, xln);
            gemm64_kernel<2><<<dim3(SS / 64, HID / 64), 256, 0, stream>>>(xln, Wol, nullptr, ao_b, SS, HID, HID);
        }
        // ---- feed-forward (per batch, 2 chunks of 4096 rows) ----
        for (int b = 0; b < BB; ++b) {
            const float* ao_b = attn_out + (size_t)b * SS * HID;
            ln256_kernel<<<SS, 256, 0, stream>>>(ao_b, g2l, b2l, xln);
            for (int half = 0; half < 2; ++half) {
                const float* Ain = xln + (size_t)half * 4096 * HID;
                float* Hout = hidden + (size_t)b * SS * HID + (size_t)half * 4096 * HID;
                gemm64_kernel<1><<<dim3(4096 / 64, FFD / 64), 256, 0, stream>>>(Ain, W1l, bf1l, bigB, 4096, FFD, HID);
                gemm64_kernel<3><<<dim3(4096 / 64, HID / 64), 256, 0, stream>>>(bigB, W2l, bf2l, Hout, 4096, HID, FFD);
            }
        }
    }
    ln512_kernel<<<BB * SS, 256, 0, stream>>>(attn_out, hidden, gf, bff, (float*)d_out);
}

// Round 3
// 3582.351 us; speedup vs baseline: 3.4607x; 3.4607x over previous
//
#include <hip/hip_runtime.h>
#include <math.h>

#define BB 4
#define SS 8192
#define HID 256
#define NHEADS 4
#define DH 64
#define FFD 1024
#define NLAYERS 2
#define NHASH 2
#define NBUCK 128
#define NROT 64          // NBUCK/2
#define NSEQ (NHASH*SS)  // 16384
#define NCH (NSEQ/64)    // 256 chunks of 64
#define MASKVAL -1e5f

// ---------------- block reduce (256 threads = 4 waves) ----------------
__device__ __forceinline__ float block_reduce_sum(float v, float* red) {
#pragma unroll
    for (int off = 32; off; off >>= 1) v += __shfl_down(v, off);
    int lane = threadIdx.x & 63, wid = threadIdx.x >> 6;
    __syncthreads();
    if (lane == 0) red[wid] = v;
    __syncthreads();
    return red[0] + red[1] + red[2] + red[3];
}

// ---------------- LayerNorm over 256 ----------------
__global__ void ln256_kernel(const float* __restrict__ x, const float* __restrict__ g,
                             const float* __restrict__ b, float* __restrict__ y) {
    int row = blockIdx.x, tid = threadIdx.x;
    __shared__ float red[4];
    float v = x[(size_t)row * HID + tid];
    float mu = block_reduce_sum(v, red) * (1.f / 256.f);
    float d = v - mu;
    float var = block_reduce_sum(d * d, red) * (1.f / 256.f);
    y[(size_t)row * HID + tid] = d * rsqrtf(var + 1e-12f) * g[tid] + b[tid];
}

// ---------------- Final LayerNorm over concat(512) ----------------
__global__ void ln512_kernel(const float* __restrict__ a, const float* __restrict__ hd,
                             const float* __restrict__ g, const float* __restrict__ b,
                             float* __restrict__ out) {
    int row = blockIdx.x, tid = threadIdx.x;
    __shared__ float red[4];
    float x0 = a[(size_t)row * HID + tid];
    float x1 = hd[(size_t)row * HID + tid];
    float mu = block_reduce_sum(x0 + x1, red) * (1.f / 512.f);
    float d0 = x0 - mu, d1 = x1 - mu;
    float var = block_reduce_sum(d0 * d0 + d1 * d1, red) * (1.f / 512.f);
    float r = rsqrtf(var + 1e-12f);
    out[(size_t)row * 512 + tid]       = d0 * r * g[tid] + b[tid];
    out[(size_t)row * 512 + 256 + tid] = d1 * r * g[256 + tid] + b[256 + tid];
}

// ---------------- fp32 tiled GEMM: C[M,N] = A[M,K] @ B[K,N] (+epilogue) ----------------
// EPI: 0 = store, 1 = store relu(acc+bias), 2 = C += acc, 3 = C += acc + bias
template <int EPI>
__global__ __launch_bounds__(256) void gemm64_kernel(
    const float* __restrict__ A, const float* __restrict__ Bm,
    const float* __restrict__ bias, float* __restrict__ C,
    int M, int N, int K) {
    __shared__ float As[16][64];
    __shared__ float Bs[16][64];
    int bm = blockIdx.x * 64, bn = blockIdx.y * 64;
    int tid = threadIdx.x;
    int tx = tid & 15, ty = tid >> 4;
    float acc[4][4] = {};
    for (int k0 = 0; k0 < K; k0 += 16) {
#pragma unroll
        for (int t = 0; t < 4; ++t) {
            int e = tid + t * 256;
            int m = e >> 4, kk = e & 15;
            As[kk][m] = A[(size_t)(bm + m) * K + k0 + kk];
        }
#pragma unroll
        for (int t = 0; t < 4; ++t) {
            int e = tid + t * 256;
            int kk = e >> 6, n = e & 63;
            Bs[kk][n] = Bm[(size_t)(k0 + kk) * N + bn + n];
        }
        __syncthreads();
#pragma unroll
        for (int kk = 0; kk < 16; ++kk) {
            float a0[4], b0[4];
#pragma unroll
            for (int i = 0; i < 4; ++i) a0[i] = As[kk][ty * 4 + i];
#pragma unroll
            for (int j = 0; j < 4; ++j) b0[j] = Bs[kk][tx * 4 + j];
#pragma unroll
            for (int i = 0; i < 4; ++i)
#pragma unroll
                for (int j = 0; j < 4; ++j) acc[i][j] += a0[i] * b0[j];
        }
        __syncthreads();
    }
#pragma unroll
    for (int i = 0; i < 4; ++i) {
        int m = bm + ty * 4 + i;
        float* Cr = C + (size_t)m * N + bn + tx * 4;
#pragma unroll
        for (int j = 0; j < 4; ++j) {
            float val = acc[i][j];
            if (EPI == 1)      { val += bias[bn + tx * 4 + j]; Cr[j] = fmaxf(val, 0.f); }
            else if (EPI == 2) { Cr[j] += val; }
            else if (EPI == 3) { Cr[j] += val + bias[bn + tx * 4 + j]; }
            else               { Cr[j] = val; }
        }
    }
}

// ---------------- LSH hash, tiled: one block = 64 s-rows x 128 rot-cols, per head ----------------
// qk is per-batch [S,HID]; buckets per-batch [H,NSEQ]
__global__ __launch_bounds__(256) void hash_kernel(const float* __restrict__ qk,
                                                   const float* __restrict__ rot,
                                                   int* __restrict__ buckets) {
    __shared__ float QsT[64][68];     // [d][row] transposed Q tile
    __shared__ float rotLDS[64][132]; // [d][col], col = n*64 + r (matches rot memory order)
    int s0 = blockIdx.x * 64;
    int h = blockIdx.y;
    int tid = threadIdx.x;
    // load Q tile (64 rows x 64 d), store transposed
#pragma unroll
    for (int t = 0; t < 4; ++t) {
        int e = tid + t * 256;
        int r = e >> 4, c4 = e & 15;
        float4 f = *(const float4*)(qk + (size_t)(s0 + r) * HID + h * DH + c4 * 4);
        QsT[c4 * 4 + 0][r] = f.x;
        QsT[c4 * 4 + 1][r] = f.y;
        QsT[c4 * 4 + 2][r] = f.z;
        QsT[c4 * 4 + 3][r] = f.w;
    }
    // load rot[h]: [64 d][128 cols] contiguous per d
    const float* rp = rot + (size_t)h * DH * NHASH * NROT;
#pragma unroll
    for (int t = 0; t < 8; ++t) {
        int e = tid + t * 256;
        int d = e >> 5, c4 = e & 31;
        *(float4*)&rotLDS[d][c4 * 4] = *(const float4*)(rp + d * 128 + c4 * 4);
    }
    __syncthreads();
    int tx = tid & 15, ty = tid >> 4;  // tx: 8-col group (tx>>3 = hash round), ty: 4-row group
    float acc[4][8] = {};
#pragma unroll 2
    for (int d = 0; d < 64; ++d) {
        float a_[4];
#pragma unroll
        for (int i = 0; i < 4; ++i) a_[i] = QsT[d][ty * 4 + i];
        float4 b0 = *(float4*)&rotLDS[d][tx * 8];
        float4 b1 = *(float4*)&rotLDS[d][tx * 8 + 4];
#pragma unroll
        for (int i = 0; i < 4; ++i) {
            acc[i][0] += a_[i] * b0.x; acc[i][1] += a_[i] * b0.y;
            acc[i][2] += a_[i] * b0.z; acc[i][3] += a_[i] * b0.w;
            acc[i][4] += a_[i] * b1.x; acc[i][5] += a_[i] * b1.y;
            acc[i][6] += a_[i] * b1.z; acc[i][7] += a_[i] * b1.w;
        }
    }
    // argmax over [rot, -rot] per (row, hash round); tx groups of 8 cover one round
    int n = tx >> 3;
#pragma unroll
    for (int i = 0; i < 4; ++i) {
        float bp = -3.4e38f, bn = -3.4e38f;
        int ipx = 0, inx = 0;
#pragma unroll
        for (int j = 0; j < 8; ++j) {
            float v = acc[i][j];
            int r = ((tx & 7) * 8 + j);  // col within this hash round, 0..63
            if (v > bp)  { bp = v;  ipx = r; }
            if (-v > bn) { bn = -v; inx = r; }
        }
        // reduce across the 8 threads of this round (lane bits 0..2), first-index tie-break
#pragma unroll
        for (int mask = 1; mask <= 4; mask <<= 1) {
            float obp = __shfl_xor(bp, mask); int oip = __shfl_xor(ipx, mask);
            float obn = __shfl_xor(bn, mask); int oin = __shfl_xor(inx, mask);
            if (obp > bp || (obp == bp && oip < ipx)) { bp = obp; ipx = oip; }
            if (obn > bn || (obn == bn && oin < inx)) { bn = obn; inx = oin; }
        }
        if ((tx & 7) == 0) {
            int bucket = (bn > bp) ? (NROT + inx) : ipx;
            buckets[h * NSEQ + n * SS + s0 + ty * 4 + i] = bucket + n * NBUCK;
        }
    }
}

// ---------------- parallel stable counting sort (one block per head) ----------------
// 64 threads; thread t owns contiguous items [t*256, (t+1)*256) -> stability preserved.
__global__ __launch_bounds__(64) void sort_kernel(const int* __restrict__ buckets,
                                                  int* __restrict__ sort_idx,
                                                  int* __restrict__ inv) {
    int bh = blockIdx.x;
    const int* bk = buckets + (size_t)bh * NSEQ;
    int* sj = sort_idx + (size_t)bh * NSEQ;
    int* ij = inv + (size_t)bh * NSEQ;
    __shared__ unsigned short cnt[256][66];  // [bin][thread-column], padded
    __shared__ int colsum[256];
    int tid = threadIdx.x;
    for (int t = tid; t < 256 * 66; t += 64) (&cnt[0][0])[t] = 0;
    __syncthreads();
    int base = tid * 256;
    for (int j = 0; j < 256; j += 4) {
        int4 b4 = *(const int4*)(bk + base + j);
        cnt[b4.x][tid]++; cnt[b4.y][tid]++; cnt[b4.z][tid]++; cnt[b4.w][tid]++;
    }
    __syncthreads();
    // per-bin exclusive prefix across thread columns
    for (int jb = tid; jb < 256; jb += 64) {
        int run = 0;
        for (int tt = 0; tt < 64; ++tt) { int c = cnt[jb][tt]; cnt[jb][tt] = (unsigned short)run; run += c; }
        colsum[jb] = run;
    }
    __syncthreads();
    if (tid == 0) {
        int run = 0;
        for (int j = 0; j < 256; ++j) { int c = colsum[j]; colsum[j] = run; run += c; }
    }
    __syncthreads();
    for (int jb = tid; jb < 256; jb += 64) {
        int bs = colsum[jb];
        for (int tt = 0; tt < 64; ++tt) cnt[jb][tt] = (unsigned short)(cnt[jb][tt] + bs);
    }
    __syncthreads();
    // replay: each thread draws ranks from its own column (no contention)
    for (int j = 0; j < 256; j += 4) {
        int4 b4 = *(const int4*)(bk + base + j);
        int i0 = base + j;
        int r;
        r = cnt[b4.x][tid]++; sj[r] = i0;     ij[i0]     = r;
        r = cnt[b4.y][tid]++; sj[r] = i0 + 1; ij[i0 + 1] = r;
        r = cnt[b4.z][tid]++; sj[r] = i0 + 2; ij[i0 + 2] = r;
        r = cnt[b4.w][tid]++; sj[r] = i0 + 3; ij[i0 + 3] = r;
    }
}

// ---------------- chunked LSH attention (one block per h,chunk; per-batch slices) ----------------
#define QPAD 68
__global__ __launch_bounds__(256) void attn_kernel(
    const float* __restrict__ qk, const float* __restrict__ vv,
    const int* __restrict__ sort_idx,
    float* __restrict__ out_s, float* __restrict__ logit_s) {
    __shared__ float q_lds[64][QPAD];
    __shared__ float kv_lds[128][QPAD];
    __shared__ int qid[64];
    __shared__ int kid[128];
    int c = blockIdx.x, h = blockIdx.y;
    int tid = threadIdx.x;
    const int* si = sort_idx + (size_t)h * NSEQ;
    int cprev = (c == 0) ? (NCH - 1) : (c - 1);
    if (tid < 64) qid[tid] = si[c * 64 + tid];
    else if (tid < 192) {
        int k = tid - 64;
        kid[k] = (k < 64) ? si[cprev * 64 + k] : si[c * 64 + (k - 64)];
    }
    __syncthreads();
    // gather Q rows (64 x 64)
#pragma unroll
    for (int t = 0; t < 4; ++t) {
        int e = tid + t * 256;
        int row = e >> 4, d4 = e & 15;
        int s = qid[row] & (SS - 1);
        float4 f = *(const float4*)(qk + (size_t)s * HID + h * DH + d4 * 4);
        *(float4*)&q_lds[row][d4 * 4] = f;
    }
    // gather K rows raw (128 x 64)
#pragma unroll
    for (int t = 0; t < 8; ++t) {
        int e = tid + t * 256;
        int row = e >> 4, d4 = e & 15;
        int s = kid[row] & (SS - 1);
        float4 f = *(const float4*)(qk + (size_t)s * HID + h * DH + d4 * 4);
        *(float4*)&kv_lds[row][d4 * 4] = f;
    }
    __syncthreads();
    // len+dim normalize K rows: k = k / max(||k||,1e-12) * D^-0.5
    if (tid < 128) {
        float ssq = 0;
#pragma unroll
        for (int d = 0; d < DH; ++d) { float x = kv_lds[tid][d]; ssq += x * x; }
        float nrm = fmaxf(sqrtf(ssq), 1e-12f);
        float sc = 0.125f / nrm;
#pragma unroll
        for (int d = 0; d < DH; ++d) kv_lds[tid][d] *= sc;
    }
    __syncthreads();
    int q = tid >> 2, ks = tid & 3;
    int myqid = qid[q];
    float sc_[32];
    float m = -3.4e38f;
#pragma unroll 4
    for (int kk = 0; kk < 32; ++kk) {
        int k = ks + kk * 4;  // interleaved to avoid LDS bank conflicts
        float acc = 0;
#pragma unroll
        for (int d4 = 0; d4 < 16; ++d4) {
            float4 qa = *(float4*)&q_lds[q][d4 * 4];
            float4 ka = *(float4*)&kv_lds[k][d4 * 4];
            acc += qa.x * ka.x + qa.y * ka.y + qa.z * ka.z + qa.w * ka.w;
        }
        if (myqid == kid[k]) acc = MASKVAL;
        sc_[kk] = acc;
        m = fmaxf(m, acc);
    }
    m = fmaxf(m, __shfl_xor(m, 1));
    m = fmaxf(m, __shfl_xor(m, 2));
    float se = 0;
#pragma unroll
    for (int kk = 0; kk < 32; ++kk) se += expf(sc_[kk] - m);
    se += __shfl_xor(se, 1);
    se += __shfl_xor(se, 2);
    float logit = m + logf(se);
#pragma unroll
    for (int kk = 0; kk < 32; ++kk) sc_[kk] = expf(sc_[kk] - logit);  // probs
    __syncthreads();
    // reload V rows (raw gather)
#pragma unroll
    for (int t = 0; t < 8; ++t) {
        int e = tid + t * 256;
        int row = e >> 4, d4 = e & 15;
        int s = kid[row] & (SS - 1);
        float4 f = *(const float4*)(vv + (size_t)s * HID + h * DH + d4 * 4);
        *(float4*)&kv_lds[row][d4 * 4] = f;
    }
    __syncthreads();
    float acc[DH] = {};
#pragma unroll 4
    for (int kk = 0; kk < 32; ++kk) {
        int k = ks + kk * 4;
        float p = sc_[kk];
#pragma unroll
        for (int d4 = 0; d4 < 16; ++d4) {
            float4 va = *(float4*)&kv_lds[k][d4 * 4];
            acc[d4 * 4 + 0] += p * va.x;
            acc[d4 * 4 + 1] += p * va.y;
            acc[d4 * 4 + 2] += p * va.z;
            acc[d4 * 4 + 3] += p * va.w;
        }
    }
#pragma unroll
    for (int d = 0; d < DH; ++d) {
        acc[d] += __shfl_xor(acc[d], 1);
        acc[d] += __shfl_xor(acc[d], 2);
    }
    if (ks == 0) {
        float* dst = out_s + ((size_t)h * NSEQ + c * 64 + q) * DH;
#pragma unroll
        for (int d4 = 0; d4 < 16; ++d4)
            *(float4*)&dst[d4 * 4] = make_float4(acc[d4 * 4], acc[d4 * 4 + 1], acc[d4 * 4 + 2], acc[d4 * 4 + 3]);
        logit_s[(size_t)h * NSEQ + c * 64 + q] = logit;
    }
}

// ---------------- unsort + combine hash rounds (per-batch slices) ----------------
__global__ void combine_kernel(const float* __restrict__ out_s, const float* __restrict__ logit_s,
                               const int* __restrict__ inv, float* __restrict__ attn_comb) {
    size_t gid = (size_t)blockIdx.x * 256 + threadIdx.x;  // H*S*16 threads
    int d4 = gid & 15;
    size_t r = gid >> 4;
    int s = (int)(r & (SS - 1));
    int h = (int)(r >> 13);
    int j0 = inv[(size_t)h * NSEQ + s];
    int j1 = inv[(size_t)h * NSEQ + SS + s];
    float l0 = logit_s[(size_t)h * NSEQ + j0];
    float l1 = logit_s[(size_t)h * NSEQ + j1];
    float mx = fmaxf(l0, l1);
    float e0 = expf(l0 - mx), e1 = expf(l1 - mx);
    float is = 1.f / (e0 + e1);
    float w0 = e0 * is, w1 = e1 * is;
    float4 o0 = *(const float4*)(out_s + ((size_t)h * NSEQ + j0) * DH + d4 * 4);
    float4 o1 = *(const float4*)(out_s + ((size_t)h * NSEQ + j1) * DH + d4 * 4);
    float4 o;
    o.x = w0 * o0.x + w1 * o1.x;
    o.y = w0 * o0.y + w1 * o1.y;
    o.z = w0 * o0.z + w1 * o1.z;
    o.w = w0 * o0.w + w1 * o1.w;
    *(float4*)(attn_comb + (size_t)s * HID + h * DH + d4 * 4) = o;
}

// ---------------- launch ----------------
extern "C" void kernel_launch(void* const* d_in, const int* in_sizes, int n_in,
                              void* d_out, int out_size, void* d_ws, size_t ws_size,
                              hipStream_t stream) {
    const float* hs  = (const float*)d_in[0];
    const float* g1  = (const float*)d_in[1];
    const float* b1  = (const float*)d_in[2];
    const float* Wqk = (const float*)d_in[3];
    const float* Wv  = (const float*)d_in[4];
    const float* Wo  = (const float*)d_in[5];
    const float* rot = (const float*)d_in[6];
    const float* g2  = (const float*)d_in[7];
    const float* b2  = (const float*)d_in[8];
    const float* W1  = (const float*)d_in[9];
    const float* bf1 = (const float*)d_in[10];
    const float* W2  = (const float*)d_in[11];
    const float* bf2 = (const float*)d_in[12];
    const float* gf  = (const float*)d_in[13];
    const float* bff = (const float*)d_in[14];

    const size_t NE  = (size_t)BB * SS * HID;   // 8,388,608 floats
    const size_t NB4 = NE / 4;                  // per-batch [S,HID] = 2,097,152
    float* f = (float*)d_ws;
    float* attn_out = f;                 // [B,S,HID]  persistent
    float* hidden   = f + NE;            // [B,S,HID]  persistent
    float* xln      = f + 2 * NE;        // [S,HID] per-batch (x_ln / comb / h_ln)
    float* bigB     = f + 2 * NE + NB4;  // NE/2: qk_b | v_b, later ffbuf [4096,1024]
    float* qk_b     = bigB;
    float* v_b      = bigB + NB4;
    float* logit_b  = f + 2 * NE + NB4 + NE / 2;            // [H,NSEQ] = 65536
    int*   sort_b   = (int*)(logit_b + (size_t)NHEADS * NSEQ);
    int*   inv_b    = sort_b + (size_t)NHEADS * NSEQ;
    int*   buck_b   = inv_b + (size_t)NHEADS * NSEQ;
    // total ws usage: 2.75*NE + 4*65536 floats  ~= 89.3 MB

    float* outsort = (float*)d_out;  // reuse d_out as [B][H,NSEQ,DH] scratch (16.78M floats)

    hipMemcpyAsync(attn_out, hs, NE * 4, hipMemcpyDeviceToDevice, stream);
    hipMemcpyAsync(hidden, hs, NE * 4, hipMemcpyDeviceToDevice, stream);

    for (int l = 0; l < NLAYERS; ++l) {
        const float* g1l = g1 + l * HID;
        const float* b1l = b1 + l * HID;
        const float* Wqkl = Wqk + (size_t)l * HID * HID;
        const float* Wvl  = Wv + (size_t)l * HID * HID;
        const float* Wol  = Wo + (size_t)l * HID * HID;
        const float* rotl = rot + (size_t)l * NHEADS * DH * NHASH * NROT;
        const float* g2l = g2 + l * HID;
        const float* b2l = b2 + l * HID;
        const float* W1l = W1 + (size_t)l * HID * FFD;
        const float* bf1l = bf1 + l * FFD;
        const float* W2l = W2 + (size_t)l * FFD * HID;
        const float* bf2l = bf2 + l * HID;

        // ---- attention (per batch to bound workspace) ----
        for (int b = 0; b < BB; ++b) {
            const float* hid_b = hidden + (size_t)b * SS * HID;
            float* ao_b = attn_out + (size_t)b * SS * HID;
            float* outs_b = outsort + (size_t)b * NHEADS * NSEQ * DH;
            ln256_kernel<<<SS, 256, 0, stream>>>(hid_b, g1l, b1l, xln);
            gemm64_kernel<0><<<dim3(SS / 64, HID / 64), 256, 0, stream>>>(xln, Wqkl, nullptr, qk_b, SS, HID, HID);
            gemm64_kernel<0><<<dim3(SS / 64, HID / 64), 256, 0, stream>>>(xln, Wvl, nullptr, v_b, SS, HID, HID);
            hash_kernel<<<dim3(SS / 64, NHEADS), 256, 0, stream>>>(qk_b, rotl, buck_b);
            sort_kernel<<<NHEADS, 64, 0, stream>>>(buck_b, sort_b, inv_b);
            attn_kernel<<<dim3(NCH, NHEADS), 256, 0, stream>>>(qk_b, v_b, sort_b, outs_b, logit_b);
            combine_kernel<<<(NHEADS * SS * 16) / 256, 256, 0, stream>>>(outs_b, logit_b, inv_b, xln);
            gemm64_kernel<2><<<dim3(SS / 64, HID / 64), 256, 0, stream>>>(xln, Wol, nullptr, ao_b, SS, HID, HID);
        }
        // ---- feed-forward (per batch, 2 chunks of 4096 rows) ----
        for (int b = 0; b < BB; ++b) {
            const float* ao_b = attn_out + (size_t)b * SS * HID;
            ln256_kernel<<<SS, 256, 0, stream>>>(ao_b, g2l, b2l, xln);
            for (int half = 0; half < 2; ++half) {
                const float* Ain = xln + (size_t)half * 4096 * HID;
                float* Hout = hidden + (size_t)b * SS * HID + (size_t)half * 4096 * HID;
                gemm64_kernel<1><<<dim3(4096 / 64, FFD / 64), 256, 0, stream>>>(Ain, W1l, bf1l, bigB, 4096, FFD, HID);
                gemm64_kernel<3><<<dim3(4096 / 64, HID / 64), 256, 0, stream>>>(bigB, W2l, bf2l, Hout, 4096, HID, FFD);
            }
        }
    }
    ln512_kernel<<<BB * SS, 256, 0, stream>>>(attn_out, hidden, gf, bff, (float*)d_out);
}

// Round 4
// 2100.236 us; speedup vs baseline: 5.9028x; 1.7057x over previous
//
#include <hip/hip_runtime.h>
#include <math.h>

#define BB 4
#define SS 8192
#define HID 256
#define NHEADS 4
#define DH 64
#define FFD 1024
#define NLAYERS 2
#define NHASH 2
#define NBUCK 128
#define NROT 64          // NBUCK/2
#define NSEQ (NHASH*SS)  // 16384
#define NCH (NSEQ/64)    // 256 chunks of 64
#define MASKVAL -1e5f

typedef __bf16 bf16x8 __attribute__((ext_vector_type(8)));
typedef float f32x4 __attribute__((ext_vector_type(4)));

__device__ __forceinline__ unsigned short f2bf(float x) {
    unsigned u = __float_as_uint(x);
    unsigned r = (u >> 16) & 1;
    u += 0x7fffu + r;              // RNE
    return (unsigned short)(u >> 16);
}
__device__ __forceinline__ float bf2f(unsigned short h) {
    return __uint_as_float(((unsigned)h) << 16);
}

// ---------------- block reduce (256 threads = 4 waves) ----------------
__device__ __forceinline__ float block_reduce_sum(float v, float* red) {
#pragma unroll
    for (int off = 32; off; off >>= 1) v += __shfl_down(v, off);
    int lane = threadIdx.x & 63, wid = threadIdx.x >> 6;
    __syncthreads();
    if (lane == 0) red[wid] = v;
    __syncthreads();
    return red[0] + red[1] + red[2] + red[3];
}

// ---------------- LayerNorm over 256, optional f32/bf16 outputs ----------------
template <bool F32OUT, bool BFOUT>
__global__ void ln256_kernel(const float* __restrict__ x, const float* __restrict__ g,
                             const float* __restrict__ b, float* __restrict__ y,
                             unsigned short* __restrict__ ybf) {
    int row = blockIdx.x, tid = threadIdx.x;
    __shared__ float red[4];
    float v = x[(size_t)row * HID + tid];
    float mu = block_reduce_sum(v, red) * (1.f / 256.f);
    float d = v - mu;
    float var = block_reduce_sum(d * d, red) * (1.f / 256.f);
    float out = d * rsqrtf(var + 1e-12f) * g[tid] + b[tid];
    if (F32OUT) y[(size_t)row * HID + tid] = out;
    if (BFOUT)  ybf[(size_t)row * HID + tid] = f2bf(out);
}

// ---------------- Final LayerNorm over concat(512) ----------------
__global__ void ln512_kernel(const float* __restrict__ a, const float* __restrict__ hd,
                             const float* __restrict__ g, const float* __restrict__ b,
                             float* __restrict__ out) {
    int row = blockIdx.x, tid = threadIdx.x;
    __shared__ float red[4];
    float x0 = a[(size_t)row * HID + tid];
    float x1 = hd[(size_t)row * HID + tid];
    float mu = block_reduce_sum(x0 + x1, red) * (1.f / 512.f);
    float d0 = x0 - mu, d1 = x1 - mu;
    float var = block_reduce_sum(d0 * d0 + d1 * d1, red) * (1.f / 512.f);
    float r = rsqrtf(var + 1e-12f);
    out[(size_t)row * 512 + tid]       = d0 * r * g[tid] + b[tid];
    out[(size_t)row * 512 + 256 + tid] = d1 * r * g[256 + tid] + b[256 + tid];
}

// ---------------- weight transpose + f32->bf16: W[K,N] -> Wt[N,K] ----------------
__global__ void wconv_kernel(const float* __restrict__ W, unsigned short* __restrict__ Wt,
                             int K, int N) {
    __shared__ float t[32][33];
    int k0 = blockIdx.x * 32, n0 = blockIdx.y * 32;
    int tx = threadIdx.x & 31, ty = threadIdx.x >> 5;  // 32 x 8
#pragma unroll
    for (int i = 0; i < 32; i += 8) t[ty + i][tx] = W[(size_t)(k0 + ty + i) * N + n0 + tx];
    __syncthreads();
#pragma unroll
    for (int i = 0; i < 32; i += 8) Wt[(size_t)(n0 + ty + i) * K + k0 + tx] = f2bf(t[tx][ty + i]);
}

// ---------------- fp32 tiled GEMM (kept for the hash-critical Wqk projection) ----------------
template <int EPI>  // 0 = store
__global__ __launch_bounds__(256) void gemm64_kernel(
    const float* __restrict__ A, const float* __restrict__ Bm,
    const float* __restrict__ bias, float* __restrict__ C,
    int M, int N, int K) {
    __shared__ float As[16][64];
    __shared__ float Bs[16][64];
    int bm = blockIdx.x * 64, bn = blockIdx.y * 64;
    int tid = threadIdx.x;
    int tx = tid & 15, ty = tid >> 4;
    float acc[4][4] = {};
    for (int k0 = 0; k0 < K; k0 += 16) {
#pragma unroll
        for (int t = 0; t < 4; ++t) {
            int e = tid + t * 256;
            int m = e >> 4, kk = e & 15;
            As[kk][m] = A[(size_t)(bm + m) * K + k0 + kk];
        }
#pragma unroll
        for (int t = 0; t < 4; ++t) {
            int e = tid + t * 256;
            int kk = e >> 6, n = e & 63;
            Bs[kk][n] = Bm[(size_t)(k0 + kk) * N + bn + n];
        }
        __syncthreads();
#pragma unroll
        for (int kk = 0; kk < 16; ++kk) {
            float a0[4], b0[4];
#pragma unroll
            for (int i = 0; i < 4; ++i) a0[i] = As[kk][ty * 4 + i];
#pragma unroll
            for (int j = 0; j < 4; ++j) b0[j] = Bs[kk][tx * 4 + j];
#pragma unroll
            for (int i = 0; i < 4; ++i)
#pragma unroll
                for (int j = 0; j < 4; ++j) acc[i][j] += a0[i] * b0[j];
        }
        __syncthreads();
    }
#pragma unroll
    for (int i = 0; i < 4; ++i) {
        int m = bm + ty * 4 + i;
        float* Cr = C + (size_t)m * N + bn + tx * 4;
#pragma unroll
        for (int j = 0; j < 4; ++j) Cr[j] = acc[i][j];
    }
}

// ---------------- bf16 MFMA GEMM: C[M,N] = A[M,K] @ Bt[N,K]^T (+epilogue) ----------------
// A, Bt are bf16 (ushort). EPI: 0 = store f32, 1 = bias+relu -> bf16,
// 2 = f32 C += acc, 3 = f32 C += acc + bias, 4 = store bf16
template <int EPI>
__global__ __launch_bounds__(256) void mfma_gemm(
    const unsigned short* __restrict__ A, const unsigned short* __restrict__ Bt,
    const float* __restrict__ bias, void* __restrict__ Cv,
    int M, int N, int K) {
    __shared__ unsigned short Asl[128 * 64];  // 16 KB, XOR-swizzled rows
    __shared__ unsigned short Bsl[128 * 64];  // 16 KB
    int bm = blockIdx.x * 128, bn = blockIdx.y * 128;
    int tid = threadIdx.x;
    int wave = tid >> 6, lane = tid & 63;
    int wm = (wave >> 1) * 64, wn = (wave & 1) * 64;
    int lrow = lane & 15, lk = lane >> 4;
    f32x4 zero = {0.f, 0.f, 0.f, 0.f};
    f32x4 acc[4][4];
#pragma unroll
    for (int i = 0; i < 4; ++i)
#pragma unroll
        for (int j = 0; j < 4; ++j) acc[i][j] = zero;

    for (int k0 = 0; k0 < K; k0 += 64) {
#pragma unroll
        for (int t = 0; t < 4; ++t) {               // stage A tile: 128 rows x 64 k
            int e = tid + t * 256;                  // 0..1023
            int r = e >> 3, kc = (e & 7) * 8;
            int4 v = *(const int4*)(A + (size_t)(bm + r) * K + k0 + kc);
            *(int4*)((char*)Asl + r * 128 + ((kc * 2) ^ ((r & 7) << 4))) = v;
        }
#pragma unroll
        for (int t = 0; t < 4; ++t) {               // stage B^T tile: 128 n-rows x 64 k
            int e = tid + t * 256;
            int r = e >> 3, kc = (e & 7) * 8;
            int4 v = *(const int4*)(Bt + (size_t)(bn + r) * K + k0 + kc);
            *(int4*)((char*)Bsl + r * 128 + ((kc * 2) ^ ((r & 7) << 4))) = v;
        }
        __syncthreads();
#pragma unroll
        for (int kk = 0; kk < 2; ++kk) {
            int klocal = kk * 32 + lk * 8;
            bf16x8 af[4], bfv[4];
#pragma unroll
            for (int fm = 0; fm < 4; ++fm) {
                int r = wm + fm * 16 + lrow;
                af[fm] = *(const bf16x8*)((const char*)Asl + r * 128 + ((klocal * 2) ^ ((r & 7) << 4)));
            }
#pragma unroll
            for (int fn = 0; fn < 4; ++fn) {
                int r = wn + fn * 16 + lrow;
                bfv[fn] = *(const bf16x8*)((const char*)Bsl + r * 128 + ((klocal * 2) ^ ((r & 7) << 4)));
            }
#pragma unroll
            for (int fm = 0; fm < 4; ++fm)
#pragma unroll
                for (int fn = 0; fn < 4; ++fn)
                    acc[fm][fn] = __builtin_amdgcn_mfma_f32_16x16x32_bf16(af[fm], bfv[fn], acc[fm][fn], 0, 0, 0);
        }
        __syncthreads();
    }
    // epilogue: C/D layout col = lane&15, row = (lane>>4)*4 + reg
#pragma unroll
    for (int fm = 0; fm < 4; ++fm)
#pragma unroll
        for (int fn = 0; fn < 4; ++fn) {
            int col = bn + wn + fn * 16 + lrow;
#pragma unroll
            for (int r = 0; r < 4; ++r) {
                int row = bm + wm + fm * 16 + lk * 4 + r;
                float v = acc[fm][fn][r];
                if (EPI == 0) {
                    ((float*)Cv)[(size_t)row * N + col] = v;
                } else if (EPI == 1) {
                    v += bias[col]; v = fmaxf(v, 0.f);
                    ((unsigned short*)Cv)[(size_t)row * N + col] = f2bf(v);
                } else if (EPI == 2) {
                    ((float*)Cv)[(size_t)row * N + col] += v;
                } else if (EPI == 3) {
                    ((float*)Cv)[(size_t)row * N + col] += v + bias[col];
                } else {
                    ((unsigned short*)Cv)[(size_t)row * N + col] = f2bf(v);
                }
            }
        }
}

// ---------------- LSH hash, tiled: one block = 64 s-rows x 128 rot-cols, per head ----------------
__global__ __launch_bounds__(256) void hash_kernel(const float* __restrict__ qk,
                                                   const float* __restrict__ rot,
                                                   int* __restrict__ buckets) {
    __shared__ float QsT[64][68];     // [d][row]
    __shared__ float rotLDS[64][132]; // [d][col]
    int s0 = blockIdx.x * 64;
    int h = blockIdx.y;
    int tid = threadIdx.x;
#pragma unroll
    for (int t = 0; t < 4; ++t) {
        int e = tid + t * 256;
        int r = e >> 4, c4 = e & 15;
        float4 f = *(const float4*)(qk + (size_t)(s0 + r) * HID + h * DH + c4 * 4);
        QsT[c4 * 4 + 0][r] = f.x;
        QsT[c4 * 4 + 1][r] = f.y;
        QsT[c4 * 4 + 2][r] = f.z;
        QsT[c4 * 4 + 3][r] = f.w;
    }
    const float* rp = rot + (size_t)h * DH * NHASH * NROT;
#pragma unroll
    for (int t = 0; t < 8; ++t) {
        int e = tid + t * 256;
        int d = e >> 5, c4 = e & 31;
        *(float4*)&rotLDS[d][c4 * 4] = *(const float4*)(rp + d * 128 + c4 * 4);
    }
    __syncthreads();
    int tx = tid & 15, ty = tid >> 4;
    float acc[4][8] = {};
#pragma unroll 2
    for (int d = 0; d < 64; ++d) {
        float a_[4];
#pragma unroll
        for (int i = 0; i < 4; ++i) a_[i] = QsT[d][ty * 4 + i];
        float4 b0 = *(float4*)&rotLDS[d][tx * 8];
        float4 b1 = *(float4*)&rotLDS[d][tx * 8 + 4];
#pragma unroll
        for (int i = 0; i < 4; ++i) {
            acc[i][0] += a_[i] * b0.x; acc[i][1] += a_[i] * b0.y;
            acc[i][2] += a_[i] * b0.z; acc[i][3] += a_[i] * b0.w;
            acc[i][4] += a_[i] * b1.x; acc[i][5] += a_[i] * b1.y;
            acc[i][6] += a_[i] * b1.z; acc[i][7] += a_[i] * b1.w;
        }
    }
    int n = tx >> 3;
#pragma unroll
    for (int i = 0; i < 4; ++i) {
        float bp = -3.4e38f, bn = -3.4e38f;
        int ipx = 0, inx = 0;
#pragma unroll
        for (int j = 0; j < 8; ++j) {
            float v = acc[i][j];
            int r = ((tx & 7) * 8 + j);
            if (v > bp)  { bp = v;  ipx = r; }
            if (-v > bn) { bn = -v; inx = r; }
        }
#pragma unroll
        for (int mask = 1; mask <= 4; mask <<= 1) {
            float obp = __shfl_xor(bp, mask); int oip = __shfl_xor(ipx, mask);
            float obn = __shfl_xor(bn, mask); int oin = __shfl_xor(inx, mask);
            if (obp > bp || (obp == bp && oip < ipx)) { bp = obp; ipx = oip; }
            if (obn > bn || (obn == bn && oin < inx)) { bn = obn; inx = oin; }
        }
        if ((tx & 7) == 0) {
            int bucket = (bn > bp) ? (NROT + inx) : ipx;
            buckets[h * NSEQ + n * SS + s0 + ty * 4 + i] = bucket + n * NBUCK;
        }
    }
}

// ---------------- parallel stable counting sort (one block per head) ----------------
__global__ __launch_bounds__(64) void sort_kernel(const int* __restrict__ buckets,
                                                  int* __restrict__ sort_idx,
                                                  int* __restrict__ inv) {
    int bh = blockIdx.x;
    const int* bk = buckets + (size_t)bh * NSEQ;
    int* sj = sort_idx + (size_t)bh * NSEQ;
    int* ij = inv + (size_t)bh * NSEQ;
    __shared__ unsigned short cnt[256][66];
    __shared__ int colsum[256];
    int tid = threadIdx.x;
    for (int t = tid; t < 256 * 66; t += 64) (&cnt[0][0])[t] = 0;
    __syncthreads();
    int base = tid * 256;
    for (int j = 0; j < 256; j += 4) {
        int4 b4 = *(const int4*)(bk + base + j);
        cnt[b4.x][tid]++; cnt[b4.y][tid]++; cnt[b4.z][tid]++; cnt[b4.w][tid]++;
    }
    __syncthreads();
    for (int jb = tid; jb < 256; jb += 64) {
        int run = 0;
        for (int tt = 0; tt < 64; ++tt) { int c = cnt[jb][tt]; cnt[jb][tt] = (unsigned short)run; run += c; }
        colsum[jb] = run;
    }
    __syncthreads();
    if (tid == 0) {
        int run = 0;
        for (int j = 0; j < 256; ++j) { int c = colsum[j]; colsum[j] = run; run += c; }
    }
    __syncthreads();
    for (int jb = tid; jb < 256; jb += 64) {
        int bs = colsum[jb];
        for (int tt = 0; tt < 64; ++tt) cnt[jb][tt] = (unsigned short)(cnt[jb][tt] + bs);
    }
    __syncthreads();
    for (int j = 0; j < 256; j += 4) {
        int4 b4 = *(const int4*)(bk + base + j);
        int i0 = base + j;
        int r;
        r = cnt[b4.x][tid]++; sj[r] = i0;     ij[i0]     = r;
        r = cnt[b4.y][tid]++; sj[r] = i0 + 1; ij[i0 + 1] = r;
        r = cnt[b4.z][tid]++; sj[r] = i0 + 2; ij[i0 + 2] = r;
        r = cnt[b4.w][tid]++; sj[r] = i0 + 3; ij[i0 + 3] = r;
    }
}

// ---------------- chunked LSH attention (V is bf16) ----------------
#define QPAD 68
__global__ __launch_bounds__(256) void attn_kernel(
    const float* __restrict__ qk, const unsigned short* __restrict__ vv,
    const int* __restrict__ sort_idx,
    float* __restrict__ out_s, float* __restrict__ logit_s) {
    __shared__ float q_lds[64][QPAD];
    __shared__ float kv_lds[128][QPAD];
    __shared__ int qid[64];
    __shared__ int kid[128];
    int c = blockIdx.x, h = blockIdx.y;
    int tid = threadIdx.x;
    const int* si = sort_idx + (size_t)h * NSEQ;
    int cprev = (c == 0) ? (NCH - 1) : (c - 1);
    if (tid < 64) qid[tid] = si[c * 64 + tid];
    else if (tid < 192) {
        int k = tid - 64;
        kid[k] = (k < 64) ? si[cprev * 64 + k] : si[c * 64 + (k - 64)];
    }
    __syncthreads();
#pragma unroll
    for (int t = 0; t < 4; ++t) {
        int e = tid + t * 256;
        int row = e >> 4, d4 = e & 15;
        int s = qid[row] & (SS - 1);
        float4 f = *(const float4*)(qk + (size_t)s * HID + h * DH + d4 * 4);
        *(float4*)&q_lds[row][d4 * 4] = f;
    }
#pragma unroll
    for (int t = 0; t < 8; ++t) {
        int e = tid + t * 256;
        int row = e >> 4, d4 = e & 15;
        int s = kid[row] & (SS - 1);
        float4 f = *(const float4*)(qk + (size_t)s * HID + h * DH + d4 * 4);
        *(float4*)&kv_lds[row][d4 * 4] = f;
    }
    __syncthreads();
    if (tid < 128) {
        float ssq = 0;
#pragma unroll
        for (int d = 0; d < DH; ++d) { float x = kv_lds[tid][d]; ssq += x * x; }
        float nrm = fmaxf(sqrtf(ssq), 1e-12f);
        float sc = 0.125f / nrm;
#pragma unroll
        for (int d = 0; d < DH; ++d) kv_lds[tid][d] *= sc;
    }
    __syncthreads();
    int q = tid >> 2, ks = tid & 3;
    int myqid = qid[q];
    float sc_[32];
    float m = -3.4e38f;
#pragma unroll 4
    for (int kk = 0; kk < 32; ++kk) {
        int k = ks + kk * 4;
        float acc = 0;
#pragma unroll
        for (int d4 = 0; d4 < 16; ++d4) {
            float4 qa = *(float4*)&q_lds[q][d4 * 4];
            float4 ka = *(float4*)&kv_lds[k][d4 * 4];
            acc += qa.x * ka.x + qa.y * ka.y + qa.z * ka.z + qa.w * ka.w;
        }
        if (myqid == kid[k]) acc = MASKVAL;
        sc_[kk] = acc;
        m = fmaxf(m, acc);
    }
    m = fmaxf(m, __shfl_xor(m, 1));
    m = fmaxf(m, __shfl_xor(m, 2));
    float se = 0;
#pragma unroll
    for (int kk = 0; kk < 32; ++kk) se += expf(sc_[kk] - m);
    se += __shfl_xor(se, 1);
    se += __shfl_xor(se, 2);
    float logit = m + logf(se);
#pragma unroll
    for (int kk = 0; kk < 32; ++kk) sc_[kk] = expf(sc_[kk] - logit);
    __syncthreads();
    // reload V rows (bf16 gather, unpack to f32 LDS)
#pragma unroll
    for (int t = 0; t < 4; ++t) {
        int e = tid + t * 256;                  // 0..1023
        int row = e >> 3, d8 = e & 7;
        int s = kid[row] & (SS - 1);
        int4 raw = *(const int4*)(vv + (size_t)s * HID + h * DH + d8 * 8);
        unsigned ua[4] = {(unsigned)raw.x, (unsigned)raw.y, (unsigned)raw.z, (unsigned)raw.w};
        float4 lo, hi;
        lo.x = __uint_as_float(ua[0] << 16);           lo.y = __uint_as_float(ua[0] & 0xffff0000u);
        lo.z = __uint_as_float(ua[1] << 16);           lo.w = __uint_as_float(ua[1] & 0xffff0000u);
        hi.x = __uint_as_float(ua[2] << 16);           hi.y = __uint_as_float(ua[2] & 0xffff0000u);
        hi.z = __uint_as_float(ua[3] << 16);           hi.w = __uint_as_float(ua[3] & 0xffff0000u);
        *(float4*)&kv_lds[row][d8 * 8]     = lo;
        *(float4*)&kv_lds[row][d8 * 8 + 4] = hi;
    }
    __syncthreads();
    float acc[DH] = {};
#pragma unroll 4
    for (int kk = 0; kk < 32; ++kk) {
        int k = ks + kk * 4;
        float p = sc_[kk];
#pragma unroll
        for (int d4 = 0; d4 < 16; ++d4) {
            float4 va = *(float4*)&kv_lds[k][d4 * 4];
            acc[d4 * 4 + 0] += p * va.x;
            acc[d4 * 4 + 1] += p * va.y;
            acc[d4 * 4 + 2] += p * va.z;
            acc[d4 * 4 + 3] += p * va.w;
        }
    }
#pragma unroll
    for (int d = 0; d < DH; ++d) {
        acc[d] += __shfl_xor(acc[d], 1);
        acc[d] += __shfl_xor(acc[d], 2);
    }
    if (ks == 0) {
        float* dst = out_s + ((size_t)h * NSEQ + c * 64 + q) * DH;
#pragma unroll
        for (int d4 = 0; d4 < 16; ++d4)
            *(float4*)&dst[d4 * 4] = make_float4(acc[d4 * 4], acc[d4 * 4 + 1], acc[d4 * 4 + 2], acc[d4 * 4 + 3]);
        logit_s[(size_t)h * NSEQ + c * 64 + q] = logit;
    }
}

// ---------------- unsort + combine hash rounds -> bf16 ----------------
__global__ void combine_kernel(const float* __restrict__ out_s, const float* __restrict__ logit_s,
                               const int* __restrict__ inv, unsigned short* __restrict__ attn_comb) {
    size_t gid = (size_t)blockIdx.x * 256 + threadIdx.x;
    int d4 = gid & 15;
    size_t r = gid >> 4;
    int s = (int)(r & (SS - 1));
    int h = (int)(r >> 13);
    int j0 = inv[(size_t)h * NSEQ + s];
    int j1 = inv[(size_t)h * NSEQ + SS + s];
    float l0 = logit_s[(size_t)h * NSEQ + j0];
    float l1 = logit_s[(size_t)h * NSEQ + j1];
    float mx = fmaxf(l0, l1);
    float e0 = expf(l0 - mx), e1 = expf(l1 - mx);
    float is = 1.f / (e0 + e1);
    float w0 = e0 * is, w1 = e1 * is;
    float4 o0 = *(const float4*)(out_s + ((size_t)h * NSEQ + j0) * DH + d4 * 4);
    float4 o1 = *(const float4*)(out_s + ((size_t)h * NSEQ + j1) * DH + d4 * 4);
    ushort4 o;
    o.x = f2bf(w0 * o0.x + w1 * o1.x);
    o.y = f2bf(w0 * o0.y + w1 * o1.y);
    o.z = f2bf(w0 * o0.z + w1 * o1.z);
    o.w = f2bf(w0 * o0.w + w1 * o1.w);
    *(ushort4*)(attn_comb + (size_t)s * HID + h * DH + d4 * 4) = o;
}

// ---------------- launch ----------------
extern "C" void kernel_launch(void* const* d_in, const int* in_sizes, int n_in,
                              void* d_out, int out_size, void* d_ws, size_t ws_size,
                              hipStream_t stream) {
    const float* hs  = (const float*)d_in[0];
    const float* g1  = (const float*)d_in[1];
    const float* b1  = (const float*)d_in[2];
    const float* Wqk = (const float*)d_in[3];
    const float* Wv  = (const float*)d_in[4];
    const float* Wo  = (const float*)d_in[5];
    const float* rot = (const float*)d_in[6];
    const float* g2  = (const float*)d_in[7];
    const float* b2  = (const float*)d_in[8];
    const float* W1  = (const float*)d_in[9];
    const float* bf1 = (const float*)d_in[10];
    const float* W2  = (const float*)d_in[11];
    const float* bf2 = (const float*)d_in[12];
    const float* gf  = (const float*)d_in[13];
    const float* bff = (const float*)d_in[14];

    const size_t NE  = (size_t)BB * SS * HID;   // 8,388,608
    const size_t NB4 = NE / 4;                  // per-batch [S,HID] = 2,097,152

    // ---- d_ws layout (f32 slots): 2*NE + 262144 + 655360 = 17.7M floats (~71 MB) ----
    float* f = (float*)d_ws;
    float* attn_out = f;                     // [B,S,HID]
    float* hidden   = f + NE;                // [B,S,HID]
    float* logit_b  = f + 2 * NE;            // [H,NSEQ] = 65536
    int*   sort_b   = (int*)(logit_b + (size_t)NHEADS * NSEQ);
    int*   inv_b    = sort_b + (size_t)NHEADS * NSEQ;
    int*   buck_b   = inv_b + (size_t)NHEADS * NSEQ;
    unsigned short* wbf = (unsigned short*)(f + 2 * NE + 4 * 65536);  // 1,310,720 ushort

    // ---- d_out scratch (f32 slots, 16.77M total; all written-before-read each call) ----
    float* o = (float*)d_out;
    float* outs    = o;                                   // [H,NSEQ,DH] = 4,194,304
    unsigned short* ffbuf = (unsigned short*)(o + 4194304);  // [8192,1024] bf16
    float* qk_b    = o + 8388608;                         // [S,HID] f32
    float* xln     = o + 10485760;                        // [S,HID] f32
    unsigned short* v_bf  = (unsigned short*)(o + 12582912); // [S,HID] bf16
    unsigned short* abuf  = (unsigned short*)(o + 13631488); // [S,HID] bf16 (xln_bf/comb/h_ln)

    // per-layer transposed bf16 weight offsets within wbf (stride 655360)
    // Wv_t: +0 (65536), Wo_t: +65536, W1_t: +131072 (262144, [1024,256]), W2_t: +393216 ([256,1024])

    hipMemcpyAsync(attn_out, hs, NE * 4, hipMemcpyDeviceToDevice, stream);
    hipMemcpyAsync(hidden, hs, NE * 4, hipMemcpyDeviceToDevice, stream);

    // convert + transpose all weights to bf16 once
    for (int l = 0; l < NLAYERS; ++l) {
        unsigned short* wl = wbf + (size_t)l * 655360;
        wconv_kernel<<<dim3(HID / 32, HID / 32), 256, 0, stream>>>(Wv + (size_t)l * HID * HID, wl, HID, HID);
        wconv_kernel<<<dim3(HID / 32, HID / 32), 256, 0, stream>>>(Wo + (size_t)l * HID * HID, wl + 65536, HID, HID);
        wconv_kernel<<<dim3(HID / 32, FFD / 32), 256, 0, stream>>>(W1 + (size_t)l * HID * FFD, wl + 131072, HID, FFD);
        wconv_kernel<<<dim3(FFD / 32, HID / 32), 256, 0, stream>>>(W2 + (size_t)l * FFD * HID, wl + 393216, FFD, HID);
    }

    for (int l = 0; l < NLAYERS; ++l) {
        const float* g1l = g1 + l * HID;
        const float* b1l = b1 + l * HID;
        const float* Wqkl = Wqk + (size_t)l * HID * HID;
        const float* rotl = rot + (size_t)l * NHEADS * DH * NHASH * NROT;
        const float* g2l = g2 + l * HID;
        const float* b2l = b2 + l * HID;
        const float* bf1l = bf1 + l * FFD;
        const float* bf2l = bf2 + l * HID;
        unsigned short* Wv_t = wbf + (size_t)l * 655360;
        unsigned short* Wo_t = Wv_t + 65536;
        unsigned short* W1_t = Wv_t + 131072;
        unsigned short* W2_t = Wv_t + 393216;

        // ---- attention (per batch) ----
        for (int b = 0; b < BB; ++b) {
            const float* hid_b = hidden + (size_t)b * SS * HID;
            float* ao_b = attn_out + (size_t)b * SS * HID;
            ln256_kernel<true, true><<<SS, 256, 0, stream>>>(hid_b, g1l, b1l, xln, abuf);
            gemm64_kernel<0><<<dim3(SS / 64, HID / 64), 256, 0, stream>>>(xln, Wqkl, nullptr, qk_b, SS, HID, HID);
            mfma_gemm<4><<<dim3(SS / 128, HID / 128), 256, 0, stream>>>(abuf, Wv_t, nullptr, v_bf, SS, HID, HID);
            hash_kernel<<<dim3(SS / 64, NHEADS), 256, 0, stream>>>(qk_b, rotl, buck_b);
            sort_kernel<<<NHEADS, 64, 0, stream>>>(buck_b, sort_b, inv_b);
            attn_kernel<<<dim3(NCH, NHEADS), 256, 0, stream>>>(qk_b, v_bf, sort_b, outs, logit_b);
            combine_kernel<<<(NHEADS * SS * 16) / 256, 256, 0, stream>>>(outs, logit_b, inv_b, abuf);
            mfma_gemm<2><<<dim3(SS / 128, HID / 128), 256, 0, stream>>>(abuf, Wo_t, nullptr, ao_b, SS, HID, HID);
        }
        // ---- feed-forward (per batch) ----
        for (int b = 0; b < BB; ++b) {
            const float* ao_b = attn_out + (size_t)b * SS * HID;
            float* hid_b = hidden + (size_t)b * SS * HID;
            ln256_kernel<false, true><<<SS, 256, 0, stream>>>(ao_b, g2l, b2l, nullptr, abuf);
            mfma_gemm<1><<<dim3(SS / 128, FFD / 128), 256, 0, stream>>>(abuf, W1_t, bf1l, ffbuf, SS, FFD, HID);
            mfma_gemm<3><<<dim3(SS / 128, HID / 128), 256, 0, stream>>>(ffbuf, W2_t, bf2l, hid_b, SS, HID, FFD);
        }
    }
    ln512_kernel<<<BB * SS, 256, 0, stream>>>(attn_out, hidden, gf, bff, (float*)d_out);
}

// Round 5
// 1188.950 us; speedup vs baseline: 10.4271x; 1.7665x over previous
//
#include <hip/hip_runtime.h>
#include <math.h>

#define BB 4
#define SS 8192
#define HID 256
#define NHEADS 4
#define DH 64
#define FFD 1024
#define NLAYERS 2
#define NHASH 2
#define NBUCK 128
#define NROT 64          // NBUCK/2
#define NSEQ (NHASH*SS)  // 16384
#define NCH (NSEQ/64)    // 256 chunks of 64
#define MASKVAL -1e5f

typedef __bf16 bf16x8 __attribute__((ext_vector_type(8)));
typedef float f32x4 __attribute__((ext_vector_type(4)));

__device__ __forceinline__ unsigned short f2bf(float x) {
    unsigned u = __float_as_uint(x);
    unsigned r = (u >> 16) & 1;
    u += 0x7fffu + r;              // RNE
    return (unsigned short)(u >> 16);
}
__device__ __forceinline__ float bf2f(unsigned short h) {
    return __uint_as_float(((unsigned)h) << 16);
}

// ---------------- block reduce (256 threads = 4 waves) ----------------
__device__ __forceinline__ float block_reduce_sum(float v, float* red) {
#pragma unroll
    for (int off = 32; off; off >>= 1) v += __shfl_down(v, off);
    int lane = threadIdx.x & 63, wid = threadIdx.x >> 6;
    __syncthreads();
    if (lane == 0) red[wid] = v;
    __syncthreads();
    return red[0] + red[1] + red[2] + red[3];
}

// ---------------- LayerNorm over 256, optional f32/bf16 outputs ----------------
template <bool F32OUT, bool BFOUT>
__global__ void ln256_kernel(const float* __restrict__ x, const float* __restrict__ g,
                             const float* __restrict__ b, float* __restrict__ y,
                             unsigned short* __restrict__ ybf) {
    int row = blockIdx.x, tid = threadIdx.x;
    __shared__ float red[4];
    float v = x[(size_t)row * HID + tid];
    float mu = block_reduce_sum(v, red) * (1.f / 256.f);
    float d = v - mu;
    float var = block_reduce_sum(d * d, red) * (1.f / 256.f);
    float out = d * rsqrtf(var + 1e-12f) * g[tid] + b[tid];
    if (F32OUT) y[(size_t)row * HID + tid] = out;
    if (BFOUT)  ybf[(size_t)row * HID + tid] = f2bf(out);
}

// ---------------- Final LayerNorm over concat(512) ----------------
__global__ void ln512_kernel(const float* __restrict__ a, const float* __restrict__ hd,
                             const float* __restrict__ g, const float* __restrict__ b,
                             float* __restrict__ out) {
    int row = blockIdx.x, tid = threadIdx.x;
    __shared__ float red[4];
    float x0 = a[(size_t)row * HID + tid];
    float x1 = hd[(size_t)row * HID + tid];
    float mu = block_reduce_sum(x0 + x1, red) * (1.f / 512.f);
    float d0 = x0 - mu, d1 = x1 - mu;
    float var = block_reduce_sum(d0 * d0 + d1 * d1, red) * (1.f / 512.f);
    float r = rsqrtf(var + 1e-12f);
    out[(size_t)row * 512 + tid]       = d0 * r * g[tid] + b[tid];
    out[(size_t)row * 512 + 256 + tid] = d1 * r * g[256 + tid] + b[256 + tid];
}

// ---------------- weight transpose + f32->bf16: W[K,N] -> Wt[N,K] ----------------
__global__ void wconv_kernel(const float* __restrict__ W, unsigned short* __restrict__ Wt,
                             int K, int N) {
    __shared__ float t[32][33];
    int k0 = blockIdx.x * 32, n0 = blockIdx.y * 32;
    int tx = threadIdx.x & 31, ty = threadIdx.x >> 5;  // 32 x 8
#pragma unroll
    for (int i = 0; i < 32; i += 8) t[ty + i][tx] = W[(size_t)(k0 + ty + i) * N + n0 + tx];
    __syncthreads();
#pragma unroll
    for (int i = 0; i < 32; i += 8) Wt[(size_t)(n0 + ty + i) * K + k0 + tx] = f2bf(t[tx][ty + i]);
}

// ---------------- fp32 tiled GEMM (hash-critical Wqk projection) ----------------
template <int EPI>  // 0 = store
__global__ __launch_bounds__(256) void gemm64_kernel(
    const float* __restrict__ A, const float* __restrict__ Bm,
    const float* __restrict__ bias, float* __restrict__ C,
    int M, int N, int K) {
    __shared__ float As[16][64];
    __shared__ float Bs[16][64];
    int bm = blockIdx.x * 64, bn = blockIdx.y * 64;
    int tid = threadIdx.x;
    int tx = tid & 15, ty = tid >> 4;
    float acc[4][4] = {};
    for (int k0 = 0; k0 < K; k0 += 16) {
#pragma unroll
        for (int t = 0; t < 4; ++t) {
            int e = tid + t * 256;
            int m = e >> 4, kk = e & 15;
            As[kk][m] = A[(size_t)(bm + m) * K + k0 + kk];
        }
#pragma unroll
        for (int t = 0; t < 4; ++t) {
            int e = tid + t * 256;
            int kk = e >> 6, n = e & 63;
            Bs[kk][n] = Bm[(size_t)(k0 + kk) * N + bn + n];
        }
        __syncthreads();
#pragma unroll
        for (int kk = 0; kk < 16; ++kk) {
            float a0[4], b0[4];
#pragma unroll
            for (int i = 0; i < 4; ++i) a0[i] = As[kk][ty * 4 + i];
#pragma unroll
            for (int j = 0; j < 4; ++j) b0[j] = Bs[kk][tx * 4 + j];
#pragma unroll
            for (int i = 0; i < 4; ++i)
#pragma unroll
                for (int j = 0; j < 4; ++j) acc[i][j] += a0[i] * b0[j];
        }
        __syncthreads();
    }
#pragma unroll
    for (int i = 0; i < 4; ++i) {
        int m = bm + ty * 4 + i;
        float* Cr = C + (size_t)m * N + bn + tx * 4;
#pragma unroll
        for (int j = 0; j < 4; ++j) Cr[j] = acc[i][j];
    }
}

// ---------------- bf16 MFMA GEMM: C[M,N] = A[M,K] @ Bt[N,K]^T (+epilogue) ----------------
// EPI: 0 = store f32, 1 = bias+relu -> bf16, 2 = f32 C += acc, 3 = f32 C += acc + bias, 4 = store bf16
template <int EPI>
__global__ __launch_bounds__(256) void mfma_gemm(
    const unsigned short* __restrict__ A, const unsigned short* __restrict__ Bt,
    const float* __restrict__ bias, void* __restrict__ Cv,
    int M, int N, int K) {
    __shared__ unsigned short Asl[128 * 64];
    __shared__ unsigned short Bsl[128 * 64];
    int bm = blockIdx.x * 128, bn = blockIdx.y * 128;
    int tid = threadIdx.x;
    int wave = tid >> 6, lane = tid & 63;
    int wm = (wave >> 1) * 64, wn = (wave & 1) * 64;
    int lrow = lane & 15, lk = lane >> 4;
    f32x4 zero = {0.f, 0.f, 0.f, 0.f};
    f32x4 acc[4][4];
#pragma unroll
    for (int i = 0; i < 4; ++i)
#pragma unroll
        for (int j = 0; j < 4; ++j) acc[i][j] = zero;

    for (int k0 = 0; k0 < K; k0 += 64) {
#pragma unroll
        for (int t = 0; t < 4; ++t) {
            int e = tid + t * 256;
            int r = e >> 3, kc = (e & 7) * 8;
            int4 v = *(const int4*)(A + (size_t)(bm + r) * K + k0 + kc);
            *(int4*)((char*)Asl + r * 128 + ((kc * 2) ^ ((r & 7) << 4))) = v;
        }
#pragma unroll
        for (int t = 0; t < 4; ++t) {
            int e = tid + t * 256;
            int r = e >> 3, kc = (e & 7) * 8;
            int4 v = *(const int4*)(Bt + (size_t)(bn + r) * K + k0 + kc);
            *(int4*)((char*)Bsl + r * 128 + ((kc * 2) ^ ((r & 7) << 4))) = v;
        }
        __syncthreads();
#pragma unroll
        for (int kk = 0; kk < 2; ++kk) {
            int klocal = kk * 32 + lk * 8;
            bf16x8 af[4], bfv[4];
#pragma unroll
            for (int fm = 0; fm < 4; ++fm) {
                int r = wm + fm * 16 + lrow;
                af[fm] = *(const bf16x8*)((const char*)Asl + r * 128 + ((klocal * 2) ^ ((r & 7) << 4)));
            }
#pragma unroll
            for (int fn = 0; fn < 4; ++fn) {
                int r = wn + fn * 16 + lrow;
                bfv[fn] = *(const bf16x8*)((const char*)Bsl + r * 128 + ((klocal * 2) ^ ((r & 7) << 4)));
            }
#pragma unroll
            for (int fm = 0; fm < 4; ++fm)
#pragma unroll
                for (int fn = 0; fn < 4; ++fn)
                    acc[fm][fn] = __builtin_amdgcn_mfma_f32_16x16x32_bf16(af[fm], bfv[fn], acc[fm][fn], 0, 0, 0);
        }
        __syncthreads();
    }
#pragma unroll
    for (int fm = 0; fm < 4; ++fm)
#pragma unroll
        for (int fn = 0; fn < 4; ++fn) {
            int col = bn + wn + fn * 16 + lrow;
#pragma unroll
            for (int r = 0; r < 4; ++r) {
                int row = bm + wm + fm * 16 + lk * 4 + r;
                float v = acc[fm][fn][r];
                if (EPI == 0) {
                    ((float*)Cv)[(size_t)row * N + col] = v;
                } else if (EPI == 1) {
                    v += bias[col]; v = fmaxf(v, 0.f);
                    ((unsigned short*)Cv)[(size_t)row * N + col] = f2bf(v);
                } else if (EPI == 2) {
                    ((float*)Cv)[(size_t)row * N + col] += v;
                } else if (EPI == 3) {
                    ((float*)Cv)[(size_t)row * N + col] += v + bias[col];
                } else {
                    ((unsigned short*)Cv)[(size_t)row * N + col] = f2bf(v);
                }
            }
        }
}

// ---------------- LSH hash (unchanged, fp32) ----------------
__global__ __launch_bounds__(256) void hash_kernel(const float* __restrict__ qk,
                                                   const float* __restrict__ rot,
                                                   int* __restrict__ buckets) {
    __shared__ float QsT[64][68];
    __shared__ float rotLDS[64][132];
    int s0 = blockIdx.x * 64;
    int h = blockIdx.y;
    int tid = threadIdx.x;
#pragma unroll
    for (int t = 0; t < 4; ++t) {
        int e = tid + t * 256;
        int r = e >> 4, c4 = e & 15;
        float4 f = *(const float4*)(qk + (size_t)(s0 + r) * HID + h * DH + c4 * 4);
        QsT[c4 * 4 + 0][r] = f.x;
        QsT[c4 * 4 + 1][r] = f.y;
        QsT[c4 * 4 + 2][r] = f.z;
        QsT[c4 * 4 + 3][r] = f.w;
    }
    const float* rp = rot + (size_t)h * DH * NHASH * NROT;
#pragma unroll
    for (int t = 0; t < 8; ++t) {
        int e = tid + t * 256;
        int d = e >> 5, c4 = e & 31;
        *(float4*)&rotLDS[d][c4 * 4] = *(const float4*)(rp + d * 128 + c4 * 4);
    }
    __syncthreads();
    int tx = tid & 15, ty = tid >> 4;
    float acc[4][8] = {};
#pragma unroll 2
    for (int d = 0; d < 64; ++d) {
        float a_[4];
#pragma unroll
        for (int i = 0; i < 4; ++i) a_[i] = QsT[d][ty * 4 + i];
        float4 b0 = *(float4*)&rotLDS[d][tx * 8];
        float4 b1 = *(float4*)&rotLDS[d][tx * 8 + 4];
#pragma unroll
        for (int i = 0; i < 4; ++i) {
            acc[i][0] += a_[i] * b0.x; acc[i][1] += a_[i] * b0.y;
            acc[i][2] += a_[i] * b0.z; acc[i][3] += a_[i] * b0.w;
            acc[i][4] += a_[i] * b1.x; acc[i][5] += a_[i] * b1.y;
            acc[i][6] += a_[i] * b1.z; acc[i][7] += a_[i] * b1.w;
        }
    }
    int n = tx >> 3;
#pragma unroll
    for (int i = 0; i < 4; ++i) {
        float bp = -3.4e38f, bn = -3.4e38f;
        int ipx = 0, inx = 0;
#pragma unroll
        for (int j = 0; j < 8; ++j) {
            float v = acc[i][j];
            int r = ((tx & 7) * 8 + j);
            if (v > bp)  { bp = v;  ipx = r; }
            if (-v > bn) { bn = -v; inx = r; }
        }
#pragma unroll
        for (int mask = 1; mask <= 4; mask <<= 1) {
            float obp = __shfl_xor(bp, mask); int oip = __shfl_xor(ipx, mask);
            float obn = __shfl_xor(bn, mask); int oin = __shfl_xor(inx, mask);
            if (obp > bp || (obp == bp && oip < ipx)) { bp = obp; ipx = oip; }
            if (obn > bn || (obn == bn && oin < inx)) { bn = obn; inx = oin; }
        }
        if ((tx & 7) == 0) {
            int bucket = (bn > bp) ? (NROT + inx) : ipx;
            buckets[h * NSEQ + n * SS + s0 + ty * 4 + i] = bucket + n * NBUCK;
        }
    }
}

// ---------------- Q/K convert: q_bf = bf16(qk), k_bf = bf16(normalize(qk)) ----------------
__global__ void qknorm_kernel(const float* __restrict__ qk, unsigned short* __restrict__ qb,
                              unsigned short* __restrict__ kb) {
    int row = blockIdx.x, tid = threadIdx.x;  // 256 thr; wave = head
    float x = qk[(size_t)row * HID + tid];
    float ss = x * x;
#pragma unroll
    for (int off = 32; off; off >>= 1) ss += __shfl_xor(ss, off);
    float sc = 0.125f / fmaxf(sqrtf(ss), 1e-12f);
    qb[(size_t)row * HID + tid] = f2bf(x);
    kb[(size_t)row * HID + tid] = f2bf(x * sc);
}

// ---------------- parallel stable counting sort (one block per b,h) ----------------
__global__ __launch_bounds__(64) void sort_kernel(const int* __restrict__ buckets,
                                                  int* __restrict__ sort_idx,
                                                  int* __restrict__ inv) {
    int bh = blockIdx.x;
    const int* bk = buckets + (size_t)bh * NSEQ;
    int* sj = sort_idx + (size_t)bh * NSEQ;
    int* ij = inv + (size_t)bh * NSEQ;
    __shared__ unsigned short cnt[256][66];
    __shared__ int colsum[256];
    int tid = threadIdx.x;
    for (int t = tid; t < 256 * 66; t += 64) (&cnt[0][0])[t] = 0;
    __syncthreads();
    int base = tid * 256;
    for (int j = 0; j < 256; j += 4) {
        int4 b4 = *(const int4*)(bk + base + j);
        cnt[b4.x][tid]++; cnt[b4.y][tid]++; cnt[b4.z][tid]++; cnt[b4.w][tid]++;
    }
    __syncthreads();
    for (int jb = tid; jb < 256; jb += 64) {
        int run = 0;
        for (int tt = 0; tt < 64; ++tt) { int c = cnt[jb][tt]; cnt[jb][tt] = (unsigned short)run; run += c; }
        colsum[jb] = run;
    }
    __syncthreads();
    if (tid == 0) {
        int run = 0;
        for (int j = 0; j < 256; ++j) { int c = colsum[j]; colsum[j] = run; run += c; }
    }
    __syncthreads();
    for (int jb = tid; jb < 256; jb += 64) {
        int bs = colsum[jb];
        for (int tt = 0; tt < 64; ++tt) cnt[jb][tt] = (unsigned short)(cnt[jb][tt] + bs);
    }
    __syncthreads();
    for (int j = 0; j < 256; j += 4) {
        int4 b4 = *(const int4*)(bk + base + j);
        int i0 = base + j;
        int r;
        r = cnt[b4.x][tid]++; sj[r] = i0;     ij[i0]     = r;
        r = cnt[b4.y][tid]++; sj[r] = i0 + 1; ij[i0 + 1] = r;
        r = cnt[b4.z][tid]++; sj[r] = i0 + 2; ij[i0 + 2] = r;
        r = cnt[b4.w][tid]++; sj[r] = i0 + 3; ij[i0 + 3] = r;
    }
}

// ---------------- MFMA chunked LSH attention ----------------
// One block per (chunk, head). 4 waves; wave w owns q-rows [w*16, w*16+16).
__global__ __launch_bounds__(256) void attn_mfma(
    const unsigned short* __restrict__ qbf, const unsigned short* __restrict__ kbf,
    const unsigned short* __restrict__ vbf, const int* __restrict__ sort_idx,
    unsigned short* __restrict__ out_s, float* __restrict__ logit_s) {
    __shared__ unsigned short Qs[64][72];
    __shared__ unsigned short Ks[128][72];
    __shared__ unsigned short VT[64][136];   // V transposed: [d][k]
    __shared__ unsigned short Ps[64][136];   // probs: [q][k]
    __shared__ int qid[64];
    __shared__ int kid[128];
    int c = blockIdx.x, h = blockIdx.y;
    int tid = threadIdx.x;
    const int* si = sort_idx + (size_t)h * NSEQ;
    int cprev = (c == 0) ? (NCH - 1) : (c - 1);
    if (tid < 64) qid[tid] = si[c * 64 + tid];
    else if (tid < 192) {
        int k = tid - 64;
        kid[k] = (k < 64) ? si[cprev * 64 + k] : si[c * 64 + (k - 64)];
    }
    __syncthreads();
    // gather Q (64 rows x 8 segs of 8 bf16)
#pragma unroll
    for (int t = 0; t < 2; ++t) {
        int e = tid + t * 256;
        int row = e >> 3, seg = e & 7;
        int s = qid[row] & (SS - 1);
        *(int4*)&Qs[row][seg * 8] = *(const int4*)(qbf + ((size_t)s * HID + h * DH + seg * 8));
    }
    // gather K (normalized bf16)
#pragma unroll
    for (int t = 0; t < 4; ++t) {
        int e = tid + t * 256;
        int row = e >> 3, seg = e & 7;
        int s = kid[row] & (SS - 1);
        *(int4*)&Ks[row][seg * 8] = *(const int4*)(kbf + ((size_t)s * HID + h * DH + seg * 8));
    }
    // gather V transposed
#pragma unroll
    for (int t = 0; t < 4; ++t) {
        int e = tid + t * 256;
        int row = e >> 3, seg = e & 7;      // row = k, d0 = seg*8
        int s = kid[row] & (SS - 1);
        ushort4 a = *(const ushort4*)(vbf + ((size_t)s * HID + h * DH + seg * 8));
        ushort4 bq = *(const ushort4*)(vbf + ((size_t)s * HID + h * DH + seg * 8 + 4));
        int d0 = seg * 8;
        VT[d0 + 0][row] = a.x;  VT[d0 + 1][row] = a.y;  VT[d0 + 2][row] = a.z;  VT[d0 + 3][row] = a.w;
        VT[d0 + 4][row] = bq.x; VT[d0 + 5][row] = bq.y; VT[d0 + 6][row] = bq.z; VT[d0 + 7][row] = bq.w;
    }
    __syncthreads();
    int wave = tid >> 6, lane = tid & 63;
    int lrow = lane & 15, lk = lane >> 4;
    f32x4 zero = {0.f, 0.f, 0.f, 0.f};
    // ---- QK^T: rows wave*16.., all 128 cols ----
    f32x4 sacc[8];
#pragma unroll
    for (int fn = 0; fn < 8; ++fn) sacc[fn] = zero;
#pragma unroll
    for (int kk = 0; kk < 2; ++kk) {
        bf16x8 af = *(const bf16x8*)&Qs[wave * 16 + lrow][kk * 32 + lk * 8];
#pragma unroll
        for (int fn = 0; fn < 8; ++fn) {
            bf16x8 bv = *(const bf16x8*)&Ks[fn * 16 + lrow][kk * 32 + lk * 8];
            sacc[fn] = __builtin_amdgcn_mfma_f32_16x16x32_bf16(af, bv, sacc[fn], 0, 0, 0);
        }
    }
    // ---- mask + softmax (lane holds rows wave*16 + lk*4 + reg, cols lrow + fn*16) ----
    int myq[4];
#pragma unroll
    for (int r = 0; r < 4; ++r) myq[r] = qid[wave * 16 + lk * 4 + r];
#pragma unroll
    for (int fn = 0; fn < 8; ++fn) {
        int kv = kid[lrow + fn * 16];
#pragma unroll
        for (int r = 0; r < 4; ++r)
            if (myq[r] == kv) sacc[fn][r] = MASKVAL;
    }
    float mx[4] = {-3.4e38f, -3.4e38f, -3.4e38f, -3.4e38f};
#pragma unroll
    for (int fn = 0; fn < 8; ++fn)
#pragma unroll
        for (int r = 0; r < 4; ++r) mx[r] = fmaxf(mx[r], sacc[fn][r]);
#pragma unroll
    for (int m = 1; m <= 8; m <<= 1)
#pragma unroll
        for (int r = 0; r < 4; ++r) mx[r] = fmaxf(mx[r], __shfl_xor(mx[r], m));
    float se[4] = {0.f, 0.f, 0.f, 0.f};
#pragma unroll
    for (int fn = 0; fn < 8; ++fn)
#pragma unroll
        for (int r = 0; r < 4; ++r) se[r] += __expf(sacc[fn][r] - mx[r]);
#pragma unroll
    for (int m = 1; m <= 8; m <<= 1)
#pragma unroll
        for (int r = 0; r < 4; ++r) se[r] += __shfl_xor(se[r], m);
    float lg[4];
#pragma unroll
    for (int r = 0; r < 4; ++r) lg[r] = mx[r] + __logf(se[r]);
#pragma unroll
    for (int fn = 0; fn < 8; ++fn)
#pragma unroll
        for (int r = 0; r < 4; ++r)
            Ps[wave * 16 + lk * 4 + r][lrow + fn * 16] = f2bf(__expf(sacc[fn][r] - lg[r]));
    if (lrow == 0) {
#pragma unroll
        for (int r = 0; r < 4; ++r)
            logit_s[(size_t)h * NSEQ + c * 64 + wave * 16 + lk * 4 + r] = lg[r];
    }
    __syncthreads();
    // ---- PV: out[q][d] = P[q][k] @ V[k][d] via VT ----
    f32x4 oacc[4];
#pragma unroll
    for (int fn = 0; fn < 4; ++fn) oacc[fn] = zero;
#pragma unroll
    for (int ks = 0; ks < 4; ++ks) {
        bf16x8 af = *(const bf16x8*)&Ps[wave * 16 + lrow][ks * 32 + lk * 8];
#pragma unroll
        for (int fn = 0; fn < 4; ++fn) {
            bf16x8 bv = *(const bf16x8*)&VT[fn * 16 + lrow][ks * 32 + lk * 8];
            oacc[fn] = __builtin_amdgcn_mfma_f32_16x16x32_bf16(af, bv, oacc[fn], 0, 0, 0);
        }
    }
#pragma unroll
    for (int fn = 0; fn < 4; ++fn)
#pragma unroll
        for (int r = 0; r < 4; ++r) {
            int qrow = c * 64 + wave * 16 + lk * 4 + r;
            out_s[((size_t)h * NSEQ + qrow) * DH + lrow + fn * 16] = f2bf(oacc[fn][r]);
        }
}

// ---------------- unsort + combine hash rounds (bf16 in/out) ----------------
__global__ void combine_kernel(const unsigned short* __restrict__ out_s,
                               const float* __restrict__ logit_s,
                               const int* __restrict__ inv, unsigned short* __restrict__ attn_comb) {
    size_t gid = (size_t)blockIdx.x * 256 + threadIdx.x;
    int d4 = gid & 15;
    size_t r = gid >> 4;
    int s = (int)(r & (SS - 1));
    int h = (int)(r >> 13);
    int j0 = inv[(size_t)h * NSEQ + s];
    int j1 = inv[(size_t)h * NSEQ + SS + s];
    float l0 = logit_s[(size_t)h * NSEQ + j0];
    float l1 = logit_s[(size_t)h * NSEQ + j1];
    float mxv = fmaxf(l0, l1);
    float e0 = __expf(l0 - mxv), e1 = __expf(l1 - mxv);
    float is = 1.f / (e0 + e1);
    float w0 = e0 * is, w1 = e1 * is;
    ushort4 u0 = *(const ushort4*)(out_s + ((size_t)h * NSEQ + j0) * DH + d4 * 4);
    ushort4 u1 = *(const ushort4*)(out_s + ((size_t)h * NSEQ + j1) * DH + d4 * 4);
    ushort4 o;
    o.x = f2bf(w0 * bf2f(u0.x) + w1 * bf2f(u1.x));
    o.y = f2bf(w0 * bf2f(u0.y) + w1 * bf2f(u1.y));
    o.z = f2bf(w0 * bf2f(u0.z) + w1 * bf2f(u1.z));
    o.w = f2bf(w0 * bf2f(u0.w) + w1 * bf2f(u1.w));
    *(ushort4*)(attn_comb + (size_t)s * HID + h * DH + d4 * 4) = o;
}

// ---------------- launch ----------------
extern "C" void kernel_launch(void* const* d_in, const int* in_sizes, int n_in,
                              void* d_out, int out_size, void* d_ws, size_t ws_size,
                              hipStream_t stream) {
    const float* hs  = (const float*)d_in[0];
    const float* g1  = (const float*)d_in[1];
    const float* b1  = (const float*)d_in[2];
    const float* Wqk = (const float*)d_in[3];
    const float* Wv  = (const float*)d_in[4];
    const float* Wo  = (const float*)d_in[5];
    const float* rot = (const float*)d_in[6];
    const float* g2  = (const float*)d_in[7];
    const float* b2  = (const float*)d_in[8];
    const float* W1  = (const float*)d_in[9];
    const float* bf1 = (const float*)d_in[10];
    const float* W2  = (const float*)d_in[11];
    const float* bf2 = (const float*)d_in[12];
    const float* gf  = (const float*)d_in[13];
    const float* bff = (const float*)d_in[14];

    const size_t NE = (size_t)BB * SS * HID;    // 8,388,608
    const size_t PB = (size_t)SS * HID;         // 2,097,152 per-batch elems

    // ---- d_ws (float slots), total 22,478,848 floats ≈ 89.9 MB (< 93.3 MB proven) ----
    float* f = (float*)d_ws;
    float* attn_out = f;                         // [B,S,HID] f32
    float* hidden   = f + NE;                    // [B,S,HID] f32
    float* xlnf     = f + 2 * NE;                // [S,HID] f32 (phase A transient)
    float* qkf      = f + 2 * NE + PB;           // [S,HID] f32 (phase A) / outs_bf (phase C)
    unsigned short* outs_bf = (unsigned short*)qkf;  // [H,NSEQ,DH] bf16 = 4.19M ushort
    float* logit_b  = f + 2 * NE + 2 * PB;       // [H,NSEQ] f32 = 65536
    int*   sortx    = (int*)(logit_b + (size_t)NHEADS * NSEQ);   // [B,H,NSEQ]
    int*   invx     = sortx + (size_t)BB * NHEADS * NSEQ;
    int*   buckx    = invx + (size_t)BB * NHEADS * NSEQ;
    unsigned short* wbf = (unsigned short*)(buckx + (size_t)BB * NHEADS * NSEQ);

    // ---- d_out (16,777,216 float slots) ----
    float* o = (float*)d_out;
    unsigned short* v_bf = (unsigned short*)o;                   // [B,S,HID] bf16
    unsigned short* q_bf = (unsigned short*)(o + 4194304);       // [B,S,HID] bf16
    unsigned short* k_bf = (unsigned short*)(o + 8388608);       // [B,S,HID] bf16
    unsigned short* abuf = (unsigned short*)(o + 12582912);      // [B,S,HID] bf16 (xln/comb) ; ffbuf in phase D
    unsigned short* hln_bf = q_bf;                               // phase D reuse
    unsigned short* ffbuf  = abuf;                               // phase D reuse [8192,1024] bf16

    hipMemcpyAsync(attn_out, hs, NE * 4, hipMemcpyDeviceToDevice, stream);
    hipMemcpyAsync(hidden, hs, NE * 4, hipMemcpyDeviceToDevice, stream);

    // convert + transpose weights to bf16 once (per-layer stride 655360 ushort)
    for (int l = 0; l < NLAYERS; ++l) {
        unsigned short* wl = wbf + (size_t)l * 655360;
        wconv_kernel<<<dim3(HID / 32, HID / 32), 256, 0, stream>>>(Wv + (size_t)l * HID * HID, wl, HID, HID);
        wconv_kernel<<<dim3(HID / 32, HID / 32), 256, 0, stream>>>(Wo + (size_t)l * HID * HID, wl + 65536, HID, HID);
        wconv_kernel<<<dim3(HID / 32, FFD / 32), 256, 0, stream>>>(W1 + (size_t)l * HID * FFD, wl + 131072, HID, FFD);
        wconv_kernel<<<dim3(FFD / 32, HID / 32), 256, 0, stream>>>(W2 + (size_t)l * FFD * HID, wl + 393216, FFD, HID);
    }

    for (int l = 0; l < NLAYERS; ++l) {
        const float* g1l = g1 + l * HID;
        const float* b1l = b1 + l * HID;
        const float* Wqkl = Wqk + (size_t)l * HID * HID;
        const float* rotl = rot + (size_t)l * NHEADS * DH * NHASH * NROT;
        const float* g2l = g2 + l * HID;
        const float* b2l = b2 + l * HID;
        const float* bf1l = bf1 + l * FFD;
        const float* bf2l = bf2 + l * HID;
        unsigned short* Wv_t = wbf + (size_t)l * 655360;
        unsigned short* Wo_t = Wv_t + 65536;
        unsigned short* W1_t = Wv_t + 131072;
        unsigned short* W2_t = Wv_t + 393216;

        // ---- phase A: LN + Wqk + hash + converts (per batch), then all-batch Wv ----
        for (int b = 0; b < BB; ++b) {
            ln256_kernel<true, true><<<SS, 256, 0, stream>>>(hidden + (size_t)b * PB, g1l, b1l, xlnf, abuf + (size_t)b * PB);
            gemm64_kernel<0><<<dim3(SS / 64, HID / 64), 256, 0, stream>>>(xlnf, Wqkl, nullptr, qkf, SS, HID, HID);
            hash_kernel<<<dim3(SS / 64, NHEADS), 256, 0, stream>>>(qkf, rotl, buckx + (size_t)b * NHEADS * NSEQ);
            qknorm_kernel<<<SS, 256, 0, stream>>>(qkf, q_bf + (size_t)b * PB, k_bf + (size_t)b * PB);
        }
        mfma_gemm<4><<<dim3(BB * SS / 128, HID / 128), 256, 0, stream>>>(abuf, Wv_t, nullptr, v_bf, BB * SS, HID, HID);

        // ---- phase B: sort all (b,h) ----
        sort_kernel<<<BB * NHEADS, 64, 0, stream>>>(buckx, sortx, invx);

        // ---- phase C: attention per batch, then all-batch Wo ----
        for (int b = 0; b < BB; ++b) {
            attn_mfma<<<dim3(NCH, NHEADS), 256, 0, stream>>>(
                q_bf + (size_t)b * PB, k_bf + (size_t)b * PB, v_bf + (size_t)b * PB,
                sortx + (size_t)b * NHEADS * NSEQ, outs_bf, logit_b);
            combine_kernel<<<(NHEADS * SS * 16) / 256, 256, 0, stream>>>(
                outs_bf, logit_b, invx + (size_t)b * NHEADS * NSEQ, abuf + (size_t)b * PB);
        }
        mfma_gemm<2><<<dim3(BB * SS / 128, HID / 128), 256, 0, stream>>>(abuf, Wo_t, nullptr, attn_out, BB * SS, HID, HID);

        // ---- phase D: FF ----
        ln256_kernel<false, true><<<BB * SS, 256, 0, stream>>>(attn_out, g2l, b2l, nullptr, hln_bf);
        for (int b = 0; b < BB; ++b) {
            mfma_gemm<1><<<dim3(SS / 128, FFD / 128), 256, 0, stream>>>(hln_bf + (size_t)b * PB, W1_t, bf1l, ffbuf, SS, FFD, HID);
            mfma_gemm<3><<<dim3(SS / 128, HID / 128), 256, 0, stream>>>(ffbuf, W2_t, bf2l, hidden + (size_t)b * PB, SS, HID, FFD);
        }
    }
    ln512_kernel<<<BB * SS, 256, 0, stream>>>(attn_out, hidden, gf, bff, (float*)d_out);
}

// Round 6
// 889.288 us; speedup vs baseline: 13.9407x; 1.3370x over previous
//
#include <hip/hip_runtime.h>
#include <math.h>

#define BB 4
#define SS 8192
#define HID 256
#define NHEADS 4
#define DH 64
#define FFD 1024
#define NLAYERS 2
#define NHASH 2
#define NBUCK 128
#define NROT 64          // NBUCK/2
#define NSEQ (NHASH*SS)  // 16384
#define NCH (NSEQ/64)    // 256 chunks of 64
#define MASKVAL -1e5f

typedef __bf16 bf16x8 __attribute__((ext_vector_type(8)));
typedef float f32x4 __attribute__((ext_vector_type(4)));

__device__ __forceinline__ unsigned short f2bf(float x) {
    unsigned u = __float_as_uint(x);
    unsigned r = (u >> 16) & 1;
    u += 0x7fffu + r;              // RNE
    return (unsigned short)(u >> 16);
}
__device__ __forceinline__ float bf2f(unsigned short h) {
    return __uint_as_float(((unsigned)h) << 16);
}

// ---------------- block reduce (256 threads = 4 waves) ----------------
__device__ __forceinline__ float block_reduce_sum(float v, float* red) {
#pragma unroll
    for (int off = 32; off; off >>= 1) v += __shfl_down(v, off);
    int lane = threadIdx.x & 63, wid = threadIdx.x >> 6;
    __syncthreads();
    if (lane == 0) red[wid] = v;
    __syncthreads();
    return red[0] + red[1] + red[2] + red[3];
}

// ---------------- LayerNorm over 256 -> bf16 out, optional stats ----------------
template <bool BFOUT, bool STATS>
__global__ void ln256_kernel(const float* __restrict__ x, const float* __restrict__ g,
                             const float* __restrict__ b, unsigned short* __restrict__ ybf,
                             float* __restrict__ mu_out, float* __restrict__ rstd_out) {
    int row = blockIdx.x, tid = threadIdx.x;
    __shared__ float red[4];
    float v = x[(size_t)row * HID + tid];
    float mu = block_reduce_sum(v, red) * (1.f / 256.f);
    float d = v - mu;
    float var = block_reduce_sum(d * d, red) * (1.f / 256.f);
    float rstd = rsqrtf(var + 1e-12f);
    float out = d * rstd * g[tid] + b[tid];
    if (BFOUT) ybf[(size_t)row * HID + tid] = f2bf(out);
    if (STATS && tid == 0) { mu_out[row] = mu; rstd_out[row] = rstd; }
}

// ---------------- Final LayerNorm over concat(512) ----------------
__global__ void ln512_kernel(const float* __restrict__ a, const float* __restrict__ hd,
                             const float* __restrict__ g, const float* __restrict__ b,
                             float* __restrict__ out) {
    int row = blockIdx.x, tid = threadIdx.x;
    __shared__ float red[4];
    float x0 = a[(size_t)row * HID + tid];
    float x1 = hd[(size_t)row * HID + tid];
    float mu = block_reduce_sum(x0 + x1, red) * (1.f / 512.f);
    float d0 = x0 - mu, d1 = x1 - mu;
    float var = block_reduce_sum(d0 * d0 + d1 * d1, red) * (1.f / 512.f);
    float r = rsqrtf(var + 1e-12f);
    out[(size_t)row * 512 + tid]       = d0 * r * g[tid] + b[tid];
    out[(size_t)row * 512 + 256 + tid] = d1 * r * g[256 + tid] + b[256 + tid];
}

// ---------------- weight transpose + f32->bf16: W[K,N] -> Wt[N,K] ----------------
__global__ void wconv_kernel(const float* __restrict__ W, unsigned short* __restrict__ Wt,
                             int K, int N) {
    __shared__ float t[32][33];
    int k0 = blockIdx.x * 32, n0 = blockIdx.y * 32;
    int tx = threadIdx.x & 31, ty = threadIdx.x >> 5;  // 32 x 8
#pragma unroll
    for (int i = 0; i < 32; i += 8) t[ty + i][tx] = W[(size_t)(k0 + ty + i) * N + n0 + tx];
    __syncthreads();
#pragma unroll
    for (int i = 0; i < 32; i += 8) Wt[(size_t)(n0 + ty + i) * K + k0 + tx] = f2bf(t[tx][ty + i]);
}

// ---------------- fused fp32 Wqk GEMM + LN-on-the-fly + qk-norm + LSH hash ----------------
// One block = 64 rows (of B*S) x 64 cols (= head h). Outputs q_bf, k_bf, buckets.
__global__ __launch_bounds__(256) void qkhash_kernel(
    const float* __restrict__ hid, const float* __restrict__ mu,
    const float* __restrict__ rstd, const float* __restrict__ gamma,
    const float* __restrict__ beta, const float* __restrict__ Wqk,
    const float* __restrict__ rot, unsigned short* __restrict__ qb,
    unsigned short* __restrict__ kb, int* __restrict__ buckets) {
    __shared__ float As[16][68];      // [kk][m] LN'd activations
    __shared__ float Bs[16][68];      // [kk][n] Wqk col-slice
    __shared__ float QsT[64][68];     // [d][row] qk tile transposed
    __shared__ float rotLDS[64][132]; // [d][col]
    int bm = blockIdx.x * 64;         // row tile over B*S
    int h = blockIdx.y;
    int tid = threadIdx.x;
    int tx = tid & 15, ty = tid >> 4;
    float acc[4][4] = {};
    for (int k0 = 0; k0 < HID; k0 += 16) {
#pragma unroll
        for (int t = 0; t < 4; ++t) {
            int e = tid + t * 256;
            int m = e >> 4, kk = e & 15;
            int row = bm + m;
            float x = hid[(size_t)row * HID + k0 + kk];
            As[kk][m] = (x - mu[row]) * rstd[row] * gamma[k0 + kk] + beta[k0 + kk];
        }
#pragma unroll
        for (int t = 0; t < 4; ++t) {
            int e = tid + t * 256;
            int kk = e >> 6, n = e & 63;
            Bs[kk][n] = Wqk[(size_t)(k0 + kk) * HID + h * DH + n];
        }
        __syncthreads();
#pragma unroll
        for (int kk = 0; kk < 16; ++kk) {
            float4 a4 = *(float4*)&As[kk][ty * 4];
            float4 b4 = *(float4*)&Bs[kk][tx * 4];
            float a0[4] = {a4.x, a4.y, a4.z, a4.w};
            float b0[4] = {b4.x, b4.y, b4.z, b4.w};
#pragma unroll
            for (int i = 0; i < 4; ++i)
#pragma unroll
                for (int j = 0; j < 4; ++j) acc[i][j] += a0[i] * b0[j];
        }
        __syncthreads();
    }
    // per-row sum of squares over this head's 64 dims (reduce across tx group)
    float ssq_[4];
#pragma unroll
    for (int i = 0; i < 4; ++i) {
        float s = 0;
#pragma unroll
        for (int j = 0; j < 4; ++j) s += acc[i][j] * acc[i][j];
        ssq_[i] = s;
    }
#pragma unroll
    for (int mask = 1; mask <= 8; mask <<= 1)
#pragma unroll
        for (int i = 0; i < 4; ++i) ssq_[i] += __shfl_xor(ssq_[i], mask);
    // write q_bf / k_bf, stage QsT
#pragma unroll
    for (int i = 0; i < 4; ++i) {
        int row = bm + ty * 4 + i;
        float sc = 0.125f / fmaxf(sqrtf(ssq_[i]), 1e-12f);
        ushort4 qv, kv;
        qv.x = f2bf(acc[i][0]);      qv.y = f2bf(acc[i][1]);
        qv.z = f2bf(acc[i][2]);      qv.w = f2bf(acc[i][3]);
        kv.x = f2bf(acc[i][0] * sc); kv.y = f2bf(acc[i][1] * sc);
        kv.z = f2bf(acc[i][2] * sc); kv.w = f2bf(acc[i][3] * sc);
        *(ushort4*)(qb + (size_t)row * HID + h * DH + tx * 4) = qv;
        *(ushort4*)(kb + (size_t)row * HID + h * DH + tx * 4) = kv;
#pragma unroll
        for (int j = 0; j < 4; ++j) QsT[tx * 4 + j][ty * 4 + i] = acc[i][j];
    }
    // load rot[h]
    const float* rp = rot + (size_t)h * DH * NHASH * NROT;
#pragma unroll
    for (int t = 0; t < 8; ++t) {
        int e = tid + t * 256;
        int d = e >> 5, c4 = e & 31;
        *(float4*)&rotLDS[d][c4 * 4] = *(const float4*)(rp + d * 128 + c4 * 4);
    }
    __syncthreads();
    // hash: rotated = qk_tile @ rot, argmax over [rot, -rot]
    float acc2[4][8] = {};
#pragma unroll 2
    for (int d = 0; d < 64; ++d) {
        float4 a4 = *(float4*)&QsT[d][ty * 4];
        float a_[4] = {a4.x, a4.y, a4.z, a4.w};
        float4 b0 = *(float4*)&rotLDS[d][tx * 8];
        float4 b1v = *(float4*)&rotLDS[d][tx * 8 + 4];
#pragma unroll
        for (int i = 0; i < 4; ++i) {
            acc2[i][0] += a_[i] * b0.x;  acc2[i][1] += a_[i] * b0.y;
            acc2[i][2] += a_[i] * b0.z;  acc2[i][3] += a_[i] * b0.w;
            acc2[i][4] += a_[i] * b1v.x; acc2[i][5] += a_[i] * b1v.y;
            acc2[i][6] += a_[i] * b1v.z; acc2[i][7] += a_[i] * b1v.w;
        }
    }
    int n = tx >> 3;
#pragma unroll
    for (int i = 0; i < 4; ++i) {
        float bp = -3.4e38f, bn = -3.4e38f;
        int ipx = 0, inx = 0;
#pragma unroll
        for (int j = 0; j < 8; ++j) {
            float v = acc2[i][j];
            int r = ((tx & 7) * 8 + j);
            if (v > bp)  { bp = v;  ipx = r; }
            if (-v > bn) { bn = -v; inx = r; }
        }
#pragma unroll
        for (int mask = 1; mask <= 4; mask <<= 1) {
            float obp = __shfl_xor(bp, mask); int oip = __shfl_xor(ipx, mask);
            float obn = __shfl_xor(bn, mask); int oin = __shfl_xor(inx, mask);
            if (obp > bp || (obp == bp && oip < ipx)) { bp = obp; ipx = oip; }
            if (obn > bn || (obn == bn && oin < inx)) { bn = obn; inx = oin; }
        }
        if ((tx & 7) == 0) {
            int bucket = (bn > bp) ? (NROT + inx) : ipx;
            int row = bm + ty * 4 + i;
            int bb = row >> 13, sl = row & (SS - 1);
            buckets[(size_t)bb * NHEADS * NSEQ + h * NSEQ + n * SS + sl] = bucket + n * NBUCK;
        }
    }
}

// ---------------- bf16 MFMA GEMM: C[M,N] = A[M,K] @ Bt[N,K]^T (+epilogue) ----------------
// EPI: 1 = bias+relu -> bf16, 2 = f32 C += acc, 3 = f32 C += acc + bias, 4 = store bf16
template <int EPI>
__global__ __launch_bounds__(256) void mfma_gemm(
    const unsigned short* __restrict__ A, const unsigned short* __restrict__ Bt,
    const float* __restrict__ bias, void* __restrict__ Cv,
    int M, int N, int K) {
    __shared__ unsigned short Asl[128 * 64];
    __shared__ unsigned short Bsl[128 * 64];
    int bm = blockIdx.x * 128, bn = blockIdx.y * 128;
    int tid = threadIdx.x;
    int wave = tid >> 6, lane = tid & 63;
    int wm = (wave >> 1) * 64, wn = (wave & 1) * 64;
    int lrow = lane & 15, lk = lane >> 4;
    f32x4 zero = {0.f, 0.f, 0.f, 0.f};
    f32x4 acc[4][4];
#pragma unroll
    for (int i = 0; i < 4; ++i)
#pragma unroll
        for (int j = 0; j < 4; ++j) acc[i][j] = zero;

    for (int k0 = 0; k0 < K; k0 += 64) {
#pragma unroll
        for (int t = 0; t < 4; ++t) {
            int e = tid + t * 256;
            int r = e >> 3, kc = (e & 7) * 8;
            int4 v = *(const int4*)(A + (size_t)(bm + r) * K + k0 + kc);
            *(int4*)((char*)Asl + r * 128 + ((kc * 2) ^ ((r & 7) << 4))) = v;
        }
#pragma unroll
        for (int t = 0; t < 4; ++t) {
            int e = tid + t * 256;
            int r = e >> 3, kc = (e & 7) * 8;
            int4 v = *(const int4*)(Bt + (size_t)(bn + r) * K + k0 + kc);
            *(int4*)((char*)Bsl + r * 128 + ((kc * 2) ^ ((r & 7) << 4))) = v;
        }
        __syncthreads();
#pragma unroll
        for (int kk = 0; kk < 2; ++kk) {
            int klocal = kk * 32 + lk * 8;
            bf16x8 af[4], bfv[4];
#pragma unroll
            for (int fm = 0; fm < 4; ++fm) {
                int r = wm + fm * 16 + lrow;
                af[fm] = *(const bf16x8*)((const char*)Asl + r * 128 + ((klocal * 2) ^ ((r & 7) << 4)));
            }
#pragma unroll
            for (int fn = 0; fn < 4; ++fn) {
                int r = wn + fn * 16 + lrow;
                bfv[fn] = *(const bf16x8*)((const char*)Bsl + r * 128 + ((klocal * 2) ^ ((r & 7) << 4)));
            }
#pragma unroll
            for (int fm = 0; fm < 4; ++fm)
#pragma unroll
                for (int fn = 0; fn < 4; ++fn)
                    acc[fm][fn] = __builtin_amdgcn_mfma_f32_16x16x32_bf16(af[fm], bfv[fn], acc[fm][fn], 0, 0, 0);
        }
        __syncthreads();
    }
#pragma unroll
    for (int fm = 0; fm < 4; ++fm)
#pragma unroll
        for (int fn = 0; fn < 4; ++fn) {
            int col = bn + wn + fn * 16 + lrow;
#pragma unroll
            for (int r = 0; r < 4; ++r) {
                int row = bm + wm + fm * 16 + lk * 4 + r;
                float v = acc[fm][fn][r];
                if (EPI == 1) {
                    v += bias[col]; v = fmaxf(v, 0.f);
                    ((unsigned short*)Cv)[(size_t)row * N + col] = f2bf(v);
                } else if (EPI == 2) {
                    ((float*)Cv)[(size_t)row * N + col] += v;
                } else if (EPI == 3) {
                    ((float*)Cv)[(size_t)row * N + col] += v + bias[col];
                } else {
                    ((unsigned short*)Cv)[(size_t)row * N + col] = f2bf(v);
                }
            }
        }
}

// ---------------- parallel stable counting sort: 256 threads, one block per (b,h) ----------------
__global__ __launch_bounds__(256) void sort_kernel(const int* __restrict__ buckets,
                                                   int* __restrict__ sort_idx,
                                                   int* __restrict__ inv) {
    int bh = blockIdx.x;
    const int* bk = buckets + (size_t)bh * NSEQ;
    int* sj = sort_idx + (size_t)bh * NSEQ;
    int* ij = inv + (size_t)bh * NSEQ;
    __shared__ unsigned short cnt[256][258];  // [bin][thread-col], 132 KB
    __shared__ int colsum[256];
    int tid = threadIdx.x;
    unsigned* cz = (unsigned*)&cnt[0][0];
#pragma unroll
    for (int t = 0; t < 129; ++t) cz[tid * 129 + t] = 0;
    __syncthreads();
    int base = tid * 64;  // thread owns 64 contiguous items -> stability
    for (int j = 0; j < 64; j += 4) {
        int4 b4 = *(const int4*)(bk + base + j);
        cnt[b4.x][tid]++; cnt[b4.y][tid]++; cnt[b4.z][tid]++; cnt[b4.w][tid]++;
    }
    __syncthreads();
    {   // per-bin (bin = tid) exclusive prefix across 256 columns
        int run = 0;
        for (int c = 0; c < 256; ++c) { int v = cnt[tid][c]; cnt[tid][c] = (unsigned short)run; run += v; }
        colsum[tid] = run;
    }
    __syncthreads();
    if (tid == 0) {
        int run = 0;
        for (int j = 0; j < 256; ++j) { int c = colsum[j]; colsum[j] = run; run += c; }
    }
    __syncthreads();
    {
        int bs = colsum[tid];
        for (int c = 0; c < 256; ++c) cnt[tid][c] = (unsigned short)(cnt[tid][c] + bs);
    }
    __syncthreads();
    for (int j = 0; j < 64; j += 4) {
        int4 b4 = *(const int4*)(bk + base + j);
        int i0 = base + j;
        int r;
        r = cnt[b4.x][tid]++; sj[r] = i0;     ij[i0]     = r;
        r = cnt[b4.y][tid]++; sj[r] = i0 + 1; ij[i0 + 1] = r;
        r = cnt[b4.z][tid]++; sj[r] = i0 + 2; ij[i0 + 2] = r;
        r = cnt[b4.w][tid]++; sj[r] = i0 + 3; ij[i0 + 3] = r;
    }
}

// ---------------- MFMA chunked LSH attention ----------------
__global__ __launch_bounds__(256) void attn_mfma(
    const unsigned short* __restrict__ qbf, const unsigned short* __restrict__ kbf,
    const unsigned short* __restrict__ vbf, const int* __restrict__ sort_idx,
    unsigned short* __restrict__ out_s, float* __restrict__ logit_s) {
    __shared__ unsigned short Qs[64][72];
    __shared__ unsigned short Ks[128][72];
    __shared__ unsigned short VT[64][136];   // V transposed: [d][k]
    __shared__ unsigned short Ps[64][136];   // probs: [q][k]
    __shared__ int qid[64];
    __shared__ int kid[128];
    int c = blockIdx.x, h = blockIdx.y;
    int tid = threadIdx.x;
    const int* si = sort_idx + (size_t)h * NSEQ;
    int cprev = (c == 0) ? (NCH - 1) : (c - 1);
    if (tid < 64) qid[tid] = si[c * 64 + tid];
    else if (tid < 192) {
        int k = tid - 64;
        kid[k] = (k < 64) ? si[cprev * 64 + k] : si[c * 64 + (k - 64)];
    }
    __syncthreads();
#pragma unroll
    for (int t = 0; t < 2; ++t) {
        int e = tid + t * 256;
        int row = e >> 3, seg = e & 7;
        int s = qid[row] & (SS - 1);
        *(int4*)&Qs[row][seg * 8] = *(const int4*)(qbf + ((size_t)s * HID + h * DH + seg * 8));
    }
#pragma unroll
    for (int t = 0; t < 4; ++t) {
        int e = tid + t * 256;
        int row = e >> 3, seg = e & 7;
        int s = kid[row] & (SS - 1);
        *(int4*)&Ks[row][seg * 8] = *(const int4*)(kbf + ((size_t)s * HID + h * DH + seg * 8));
    }
#pragma unroll
    for (int t = 0; t < 4; ++t) {
        int e = tid + t * 256;
        int row = e >> 3, seg = e & 7;
        int s = kid[row] & (SS - 1);
        ushort4 a = *(const ushort4*)(vbf + ((size_t)s * HID + h * DH + seg * 8));
        ushort4 bq = *(const ushort4*)(vbf + ((size_t)s * HID + h * DH + seg * 8 + 4));
        int d0 = seg * 8;
        VT[d0 + 0][row] = a.x;  VT[d0 + 1][row] = a.y;  VT[d0 + 2][row] = a.z;  VT[d0 + 3][row] = a.w;
        VT[d0 + 4][row] = bq.x; VT[d0 + 5][row] = bq.y; VT[d0 + 6][row] = bq.z; VT[d0 + 7][row] = bq.w;
    }
    __syncthreads();
    int wave = tid >> 6, lane = tid & 63;
    int lrow = lane & 15, lk = lane >> 4;
    f32x4 zero = {0.f, 0.f, 0.f, 0.f};
    f32x4 sacc[8];
#pragma unroll
    for (int fn = 0; fn < 8; ++fn) sacc[fn] = zero;
#pragma unroll
    for (int kk = 0; kk < 2; ++kk) {
        bf16x8 af = *(const bf16x8*)&Qs[wave * 16 + lrow][kk * 32 + lk * 8];
#pragma unroll
        for (int fn = 0; fn < 8; ++fn) {
            bf16x8 bv = *(const bf16x8*)&Ks[fn * 16 + lrow][kk * 32 + lk * 8];
            sacc[fn] = __builtin_amdgcn_mfma_f32_16x16x32_bf16(af, bv, sacc[fn], 0, 0, 0);
        }
    }
    int myq[4];
#pragma unroll
    for (int r = 0; r < 4; ++r) myq[r] = qid[wave * 16 + lk * 4 + r];
#pragma unroll
    for (int fn = 0; fn < 8; ++fn) {
        int kv = kid[lrow + fn * 16];
#pragma unroll
        for (int r = 0; r < 4; ++r)
            if (myq[r] == kv) sacc[fn][r] = MASKVAL;
    }
    float mx[4] = {-3.4e38f, -3.4e38f, -3.4e38f, -3.4e38f};
#pragma unroll
    for (int fn = 0; fn < 8; ++fn)
#pragma unroll
        for (int r = 0; r < 4; ++r) mx[r] = fmaxf(mx[r], sacc[fn][r]);
#pragma unroll
    for (int m = 1; m <= 8; m <<= 1)
#pragma unroll
        for (int r = 0; r < 4; ++r) mx[r] = fmaxf(mx[r], __shfl_xor(mx[r], m));
    float se[4] = {0.f, 0.f, 0.f, 0.f};
#pragma unroll
    for (int fn = 0; fn < 8; ++fn)
#pragma unroll
        for (int r = 0; r < 4; ++r) se[r] += __expf(sacc[fn][r] - mx[r]);
#pragma unroll
    for (int m = 1; m <= 8; m <<= 1)
#pragma unroll
        for (int r = 0; r < 4; ++r) se[r] += __shfl_xor(se[r], m);
    float lg[4];
#pragma unroll
    for (int r = 0; r < 4; ++r) lg[r] = mx[r] + __logf(se[r]);
#pragma unroll
    for (int fn = 0; fn < 8; ++fn)
#pragma unroll
        for (int r = 0; r < 4; ++r)
            Ps[wave * 16 + lk * 4 + r][lrow + fn * 16] = f2bf(__expf(sacc[fn][r] - lg[r]));
    if (lrow == 0) {
#pragma unroll
        for (int r = 0; r < 4; ++r)
            logit_s[(size_t)h * NSEQ + c * 64 + wave * 16 + lk * 4 + r] = lg[r];
    }
    __syncthreads();
    f32x4 oacc[4];
#pragma unroll
    for (int fn = 0; fn < 4; ++fn) oacc[fn] = zero;
#pragma unroll
    for (int ks = 0; ks < 4; ++ks) {
        bf16x8 af = *(const bf16x8*)&Ps[wave * 16 + lrow][ks * 32 + lk * 8];
#pragma unroll
        for (int fn = 0; fn < 4; ++fn) {
            bf16x8 bv = *(const bf16x8*)&VT[fn * 16 + lrow][ks * 32 + lk * 8];
            oacc[fn] = __builtin_amdgcn_mfma_f32_16x16x32_bf16(af, bv, oacc[fn], 0, 0, 0);
        }
    }
#pragma unroll
    for (int fn = 0; fn < 4; ++fn)
#pragma unroll
        for (int r = 0; r < 4; ++r) {
            int qrow = c * 64 + wave * 16 + lk * 4 + r;
            out_s[((size_t)h * NSEQ + qrow) * DH + lrow + fn * 16] = f2bf(oacc[fn][r]);
        }
}

// ---------------- unsort + combine hash rounds (bf16 in/out) ----------------
__global__ void combine_kernel(const unsigned short* __restrict__ out_s,
                               const float* __restrict__ logit_s,
                               const int* __restrict__ inv, unsigned short* __restrict__ attn_comb) {
    size_t gid = (size_t)blockIdx.x * 256 + threadIdx.x;
    int d4 = gid & 15;
    size_t r = gid >> 4;
    int s = (int)(r & (SS - 1));
    int h = (int)(r >> 13);
    int j0 = inv[(size_t)h * NSEQ + s];
    int j1 = inv[(size_t)h * NSEQ + SS + s];
    float l0 = logit_s[(size_t)h * NSEQ + j0];
    float l1 = logit_s[(size_t)h * NSEQ + j1];
    float mxv = fmaxf(l0, l1);
    float e0 = __expf(l0 - mxv), e1 = __expf(l1 - mxv);
    float is = 1.f / (e0 + e1);
    float w0 = e0 * is, w1 = e1 * is;
    ushort4 u0 = *(const ushort4*)(out_s + ((size_t)h * NSEQ + j0) * DH + d4 * 4);
    ushort4 u1 = *(const ushort4*)(out_s + ((size_t)h * NSEQ + j1) * DH + d4 * 4);
    ushort4 o;
    o.x = f2bf(w0 * bf2f(u0.x) + w1 * bf2f(u1.x));
    o.y = f2bf(w0 * bf2f(u0.y) + w1 * bf2f(u1.y));
    o.z = f2bf(w0 * bf2f(u0.z) + w1 * bf2f(u1.z));
    o.w = f2bf(w0 * bf2f(u0.w) + w1 * bf2f(u1.w));
    *(ushort4*)(attn_comb + (size_t)s * HID + h * DH + d4 * 4) = o;
}

// ---------------- launch ----------------
extern "C" void kernel_launch(void* const* d_in, const int* in_sizes, int n_in,
                              void* d_out, int out_size, void* d_ws, size_t ws_size,
                              hipStream_t stream) {
    const float* hs  = (const float*)d_in[0];
    const float* g1  = (const float*)d_in[1];
    const float* b1  = (const float*)d_in[2];
    const float* Wqk = (const float*)d_in[3];
    const float* Wv  = (const float*)d_in[4];
    const float* Wo  = (const float*)d_in[5];
    const float* rot = (const float*)d_in[6];
    const float* g2  = (const float*)d_in[7];
    const float* b2  = (const float*)d_in[8];
    const float* W1  = (const float*)d_in[9];
    const float* bf1 = (const float*)d_in[10];
    const float* W2  = (const float*)d_in[11];
    const float* bf2 = (const float*)d_in[12];
    const float* gf  = (const float*)d_in[13];
    const float* bff = (const float*)d_in[14];

    const size_t NE = (size_t)BB * SS * HID;    // 8,388,608
    const size_t PB = (size_t)SS * HID;         // 2,097,152 per-batch elems
    const size_t MROWS = (size_t)BB * SS;       // 32768

    // ---- d_ws layout (~78.5 MB) ----
    float* f = (float*)d_ws;
    float* attn_out = f;                               // NE f32
    float* hidden   = f + NE;                          // NE f32
    float* mu       = f + 2 * NE;                      // 32768
    float* rstd     = mu + MROWS;                      // 32768
    float* logit_b  = rstd + MROWS;                    // H*NSEQ = 65536
    unsigned short* outs_bf = (unsigned short*)(logit_b + (size_t)NHEADS * NSEQ);  // H*NSEQ*DH ushort
    int* sortx = (int*)(outs_bf + (size_t)NHEADS * NSEQ * DH);  // B*H*NSEQ each
    int* invx  = sortx + (size_t)BB * NHEADS * NSEQ;
    int* buckx = invx + (size_t)BB * NHEADS * NSEQ;
    unsigned short* wbf = (unsigned short*)(buckx + (size_t)BB * NHEADS * NSEQ);   // 2*655360 ushort

    // ---- d_out scratch (64 MB = 4 slots of 16 MB) ----
    float* o = (float*)d_out;
    unsigned short* abuf = (unsigned short*)o;              // slot0: xln_bf / attn_comb / h_ln
    unsigned short* q_bf = (unsigned short*)(o + 4194304);  // slot1
    unsigned short* k_bf = (unsigned short*)(o + 8388608);  // slot2
    unsigned short* v_bf = (unsigned short*)(o + 12582912); // slot3
    unsigned short* ffbuf = q_bf;                           // phase D: slot1+slot2 = [16384,1024] bf16

    hipMemcpyAsync(attn_out, hs, NE * 4, hipMemcpyDeviceToDevice, stream);
    hipMemcpyAsync(hidden, hs, NE * 4, hipMemcpyDeviceToDevice, stream);

    for (int l = 0; l < NLAYERS; ++l) {
        unsigned short* wl = wbf + (size_t)l * 655360;
        wconv_kernel<<<dim3(HID / 32, HID / 32), 256, 0, stream>>>(Wv + (size_t)l * HID * HID, wl, HID, HID);
        wconv_kernel<<<dim3(HID / 32, HID / 32), 256, 0, stream>>>(Wo + (size_t)l * HID * HID, wl + 65536, HID, HID);
        wconv_kernel<<<dim3(HID / 32, FFD / 32), 256, 0, stream>>>(W1 + (size_t)l * HID * FFD, wl + 131072, HID, FFD);
        wconv_kernel<<<dim3(FFD / 32, HID / 32), 256, 0, stream>>>(W2 + (size_t)l * FFD * HID, wl + 393216, FFD, HID);
    }

    for (int l = 0; l < NLAYERS; ++l) {
        const float* g1l = g1 + l * HID;
        const float* b1l = b1 + l * HID;
        const float* Wqkl = Wqk + (size_t)l * HID * HID;
        const float* rotl = rot + (size_t)l * NHEADS * DH * NHASH * NROT;
        const float* g2l = g2 + l * HID;
        const float* b2l = b2 + l * HID;
        const float* bf1l = bf1 + l * FFD;
        const float* bf2l = bf2 + l * HID;
        unsigned short* Wv_t = wbf + (size_t)l * 655360;
        unsigned short* Wo_t = Wv_t + 65536;
        unsigned short* W1_t = Wv_t + 131072;
        unsigned short* W2_t = Wv_t + 393216;

        // ---- phase A (all-batch): LN(+stats) -> fused Wqk+hash+qknorm -> Wv ----
        ln256_kernel<true, true><<<MROWS, 256, 0, stream>>>(hidden, g1l, b1l, abuf, mu, rstd);
        qkhash_kernel<<<dim3(MROWS / 64, NHEADS), 256, 0, stream>>>(
            hidden, mu, rstd, g1l, b1l, Wqkl, rotl, q_bf, k_bf, buckx);
        mfma_gemm<4><<<dim3(MROWS / 128, HID / 128), 256, 0, stream>>>(abuf, Wv_t, nullptr, v_bf, MROWS, HID, HID);

        // ---- phase B: sort all (b,h) ----
        sort_kernel<<<BB * NHEADS, 256, 0, stream>>>(buckx, sortx, invx);

        // ---- phase C: attention per batch, all-batch Wo ----
        for (int b = 0; b < BB; ++b) {
            attn_mfma<<<dim3(NCH, NHEADS), 256, 0, stream>>>(
                q_bf + (size_t)b * PB, k_bf + (size_t)b * PB, v_bf + (size_t)b * PB,
                sortx + (size_t)b * NHEADS * NSEQ, outs_bf, logit_b);
            combine_kernel<<<(NHEADS * SS * 16) / 256, 256, 0, stream>>>(
                outs_bf, logit_b, invx + (size_t)b * NHEADS * NSEQ, abuf + (size_t)b * PB);
        }
        mfma_gemm<2><<<dim3(MROWS / 128, HID / 128), 256, 0, stream>>>(abuf, Wo_t, nullptr, attn_out, MROWS, HID, HID);

        // ---- phase D: FF (two M=16384 halves through 32 MB ffbuf) ----
        ln256_kernel<true, false><<<MROWS, 256, 0, stream>>>(attn_out, g2l, b2l, abuf, nullptr, nullptr);
        for (int half = 0; half < 2; ++half) {
            const unsigned short* hln_h = abuf + (size_t)half * 16384 * HID;
            float* hid_h = hidden + (size_t)half * 16384 * HID;
            mfma_gemm<1><<<dim3(16384 / 128, FFD / 128), 256, 0, stream>>>(hln_h, W1_t, bf1l, ffbuf, 16384, FFD, HID);
            mfma_gemm<3><<<dim3(16384 / 128, HID / 128), 256, 0, stream>>>(ffbuf, W2_t, bf2l, hid_h, 16384, HID, FFD);
        }
    }
    ln512_kernel<<<MROWS, 256, 0, stream>>>(attn_out, hidden, gf, bff, (float*)d_out);
}